// Round 4
// baseline (463.926 us; speedup 1.0000x reference)
//
#include <hip/hip_runtime.h>

#define S_LEN 2048
#define DM 2048
#define NH 16
#define DK 128
#define BB 2
#define BH (BB*NH)

typedef float f32x4 __attribute__((ext_vector_type(4)));
typedef __bf16 bf16x8 __attribute__((ext_vector_type(8)));
typedef unsigned int u32;

#define AS1 __attribute__((address_space(1)))
#define AS3 __attribute__((address_space(3)))

__device__ inline void gload16(const void* g, void* l){
  __builtin_amdgcn_global_load_lds((AS1 const u32*)g, (AS3 u32*)l, 16, 0, 0);
}

__device__ inline ushort f2bf(float f){
  unsigned u = __float_as_uint(f);
  u = (u + 0x7FFFu + ((u >> 16) & 1u)) >> 16;
  return (ushort)u;
}

// ---------------- fp32 -> bf16 (vectorized) ----------------
__global__ void k_f32_to_bf16(const float* __restrict__ in, ushort* __restrict__ out, int n4){
  int i = blockIdx.x * blockDim.x + threadIdx.x;
  if (i >= n4) return;
  float4 v = reinterpret_cast<const float4*>(in)[i];
  ushort4 o;
  o.x = f2bf(v.x); o.y = f2bf(v.y); o.z = f2bf(v.z); o.w = f2bf(v.w);
  reinterpret_cast<ushort4*>(out)[i] = o;
}

// ---------------- rope cos/sin table [S][64] as float2 {cos,sin} ----------------
__global__ void k_rope_table(const int* __restrict__ pos, float2* __restrict__ cs){
  int idx = blockIdx.x * 256 + threadIdx.x;
  if (idx >= S_LEN * 64) return;
  int s = idx >> 6, i = idx & 63;
  float inv = expf(-0.14391156831212787f * (float)i);   // 10000^(-i/64)
  float f = (float)pos[s] * inv;
  cs[idx] = make_float2(cosf(f), sinf(f));
}

// ---------------- fused QKV GEMM: C = xb[4096][2048] * wqkv[6144][2048]^T ----------------
// m97 structure. Epilogue: Q/K regions -> RoPE (shfl pair) -> bf16 [bh][s][d];
// V region -> bf16 transposed [bh][d][s].
__launch_bounds__(256)
__global__ void k_gemm_qkv(const ushort* __restrict__ A, const ushort* __restrict__ Bt,
                           const float2* __restrict__ cs,
                           ushort* __restrict__ Qh, ushort* __restrict__ Kh,
                           ushort* __restrict__ Vt){
  constexpr int K = 2048;
  __shared__ short lA[128 * 32];
  __shared__ short lB[128 * 32];
  const int tid = threadIdx.x;
  const int lane = tid & 63, wid = tid >> 6;
  const int wm = wid >> 1, wn = wid & 1;
  const int bx = blockIdx.x, by = blockIdx.y;
  const int fr = lane & 15, fq = lane >> 4;

  const int sr = wid * 32 + (lane >> 2);
  const int scol = (lane & 3) * 8;
  const ushort* pa = A  + (size_t)(by * 128 + sr) * K + scol;
  const ushort* pb = Bt + (size_t)(bx * 128 + sr) * K + scol;
  char* lA0 = (char*)lA + wid * 2048;
  char* lB0 = (char*)lB + wid * 2048;

  f32x4 acc[4][4] = {};
  const int arow = wm * 64, brow = wn * 64;

  for (int kk = 0; kk < K; kk += 32){
    __syncthreads();
    gload16(pa + kk,                    lA0);
    gload16(pa + (size_t)16 * K + kk,   lA0 + 1024);
    gload16(pb + kk,                    lB0);
    gload16(pb + (size_t)16 * K + kk,   lB0 + 1024);
    __syncthreads();
    bf16x8 af[4], bfr[4];
    #pragma unroll
    for (int m = 0; m < 4; m++)
      af[m] = *reinterpret_cast<const bf16x8*>(&lA[(arow + m * 16 + fr) * 32 + fq * 8]);
    #pragma unroll
    for (int n = 0; n < 4; n++)
      bfr[n] = *reinterpret_cast<const bf16x8*>(&lB[(brow + n * 16 + fr) * 32 + fq * 8]);
    #pragma unroll
    for (int m = 0; m < 4; m++)
      #pragma unroll
      for (int n = 0; n < 4; n++)
        acc[m][n] = __builtin_amdgcn_mfma_f32_16x16x32_bf16(af[m], bfr[n], acc[m][n], 0, 0, 0);
  }

  const int rowb = by * 128 + wm * 64 + fq * 4;
  if (bx < 32){
    ushort* dst = (bx < 16) ? Qh : Kh;
    #pragma unroll
    for (int m = 0; m < 4; m++)
      #pragma unroll
      for (int n = 0; n < 4; n++){
        int col = bx * 128 + wn * 64 + n * 16 + fr;
        int cg = col & 2047;
        int hh = cg >> 7, dd = cg & 127;
        int jj = (cg >> 1) & 63;
        #pragma unroll
        for (int i = 0; i < 4; i++){
          int row = rowb + m * 16 + i;
          int s = row & (S_LEN - 1), bb = row >> 11;
          float2 c2 = cs[s * 64 + jj];
          float v = acc[m][n][i];
          float p = __shfl_xor(v, 1);
          float o = (fr & 1) ? fmaf(p, c2.y, v * c2.x) : fmaf(v, c2.x, -p * c2.y);
          dst[((size_t)(bb * NH + hh) * S_LEN + s) * DK + dd] = f2bf(o);
        }
      }
  } else {
    #pragma unroll
    for (int m = 0; m < 4; m++){
      int s0 = (rowb + m * 16) & (S_LEN - 1);
      int bb = (rowb + m * 16) >> 11;
      #pragma unroll
      for (int n = 0; n < 4; n++){
        int col = (bx - 32) * 128 + wn * 64 + n * 16 + fr;
        int hh = col >> 7, dd = col & 127;
        ushort4 o;
        o.x = f2bf(acc[m][n][0]); o.y = f2bf(acc[m][n][1]);
        o.z = f2bf(acc[m][n][2]); o.w = f2bf(acc[m][n][3]);
        *reinterpret_cast<ushort4*>(&Vt[((size_t)(bb * NH + hh) * DK + dd) * S_LEN + s0]) = o;
      }
    }
  }
}

// ---------------- GEMM: C[M][N] = A[M][K] * Bt[N][K]^T  (m97 structure, fp32 out) ----------------
__launch_bounds__(256)
__global__ void k_gemm_bt(const ushort* __restrict__ A, const ushort* __restrict__ Bt,
                          float* __restrict__ C, int M, int N, int K){
  __shared__ short lA[128 * 32];
  __shared__ short lB[128 * 32];
  const int tid = threadIdx.x;
  const int lane = tid & 63, wid = tid >> 6;
  const int wm = wid >> 1, wn = wid & 1;
  const int bx = blockIdx.x, by = blockIdx.y;
  const int fr = lane & 15, fq = lane >> 4;

  const int sr = wid * 32 + (lane >> 2);
  const int scol = (lane & 3) * 8;
  const ushort* pa = A  + (size_t)(by * 128 + sr) * K + scol;
  const ushort* pb = Bt + (size_t)(bx * 128 + sr) * K + scol;
  char* lA0 = (char*)lA + wid * 2048;
  char* lB0 = (char*)lB + wid * 2048;

  f32x4 acc[4][4] = {};
  const int arow = wm * 64, brow = wn * 64;

  for (int kk = 0; kk < K; kk += 32){
    __syncthreads();
    gload16(pa + kk,                    lA0);
    gload16(pa + (size_t)16 * K + kk,   lA0 + 1024);
    gload16(pb + kk,                    lB0);
    gload16(pb + (size_t)16 * K + kk,   lB0 + 1024);
    __syncthreads();
    bf16x8 af[4], bfr[4];
    #pragma unroll
    for (int m = 0; m < 4; m++)
      af[m] = *reinterpret_cast<const bf16x8*>(&lA[(arow + m * 16 + fr) * 32 + fq * 8]);
    #pragma unroll
    for (int n = 0; n < 4; n++)
      bfr[n] = *reinterpret_cast<const bf16x8*>(&lB[(brow + n * 16 + fr) * 32 + fq * 8]);
    #pragma unroll
    for (int m = 0; m < 4; m++)
      #pragma unroll
      for (int n = 0; n < 4; n++)
        acc[m][n] = __builtin_amdgcn_mfma_f32_16x16x32_bf16(af[m], bfr[n], acc[m][n], 0, 0, 0);
  }
  const int orow = by * 128 + wm * 64 + fq * 4;
  const int ocol = bx * 128 + wn * 64 + fr;
  #pragma unroll
  for (int m = 0; m < 4; m++)
    #pragma unroll
    for (int n = 0; n < 4; n++)
      #pragma unroll
      for (int i = 0; i < 4; i++)
        C[(size_t)(orow + m * 16 + i) * N + ocol + n * 16] = acc[m][n][i];
}

// ---------------- causal flash attention: balanced paired 16-row q-tiles ----------------
// 2048 blocks x 1 wave. Block (pid,bh) processes q-tiles j=127-pid then j=pid:
// total work = (127-pid)/4 + pid/4 + 2 ~ 33 kv-tiles, uniform across blocks.
// K/V read direct global->reg (L2-resident); P via private swizzled LDS (no barriers).
__launch_bounds__(64)
__global__ void k_attn(const ushort* __restrict__ Q, const ushort* __restrict__ K,
                       const ushort* __restrict__ Vt, ushort* __restrict__ O){
  __shared__ short Pl[16 * 64];
  const int lane = threadIdx.x;
  const int bid = blockIdx.x;
  const int pid = bid >> 5;
  const int bh = bid & 31;
  const int b = bh >> 4, h = bh & 15;
  const int fr = lane & 15, fq = lane >> 4;

  const ushort* kb = K  + (size_t)bh * S_LEN * DK;
  const ushort* vb = Vt + (size_t)bh * DK * S_LEN;
  char* PlB = (char*)Pl;
  const float scale = 0.08838834764831845f;   // 1/sqrt(128)
  ushort* ob = O + (size_t)b * S_LEN * DM;

  #pragma unroll 1
  for (int half = 0; half < 2; half++){
    const int j = half ? pid : 127 - pid;
    const int qr = j * 16;

    bf16x8 qf[4];
    #pragma unroll
    for (int c = 0; c < 4; c++)
      qf[c] = *reinterpret_cast<const bf16x8*>(
          Q + ((size_t)bh * S_LEN + qr + fr) * DK + c * 32 + fq * 8);

    float mi[4], li[4];
    #pragma unroll
    for (int i = 0; i < 4; i++){ mi[i] = -1e30f; li[i] = 0.f; }
    f32x4 accO[8] = {};

    const int nt = (j >> 2) + 1;

    for (int kt = 0; kt < nt; kt++){
      const int k0 = kt * 64;

      // ---- QK^T: S[16 q][64 kv] ----
      f32x4 sc[4] = {};
      #pragma unroll
      for (int c = 0; c < 4; c++){
        bf16x8 kf[4];
        #pragma unroll
        for (int ch = 0; ch < 4; ch++)
          kf[ch] = *reinterpret_cast<const bf16x8*>(
              kb + (size_t)(k0 + ch * 16 + fr) * DK + c * 32 + fq * 8);
        #pragma unroll
        for (int ch = 0; ch < 4; ch++)
          sc[ch] = __builtin_amdgcn_mfma_f32_16x16x32_bf16(qf[c], kf[ch], sc[ch], 0, 0, 0);
      }

      // ---- scale + causal mask + online softmax ----
      const bool needmask = (k0 + 63 > qr);
      #pragma unroll
      for (int ch = 0; ch < 4; ch++)
        #pragma unroll
        for (int i = 0; i < 4; i++){
          float v = sc[ch][i] * scale;
          if (needmask && (k0 + ch * 16 + fr > qr + fq * 4 + i)) v = -1e30f;
          sc[ch][i] = v;
        }
      f32x4 mx;
      #pragma unroll
      for (int i = 0; i < 4; i++)
        mx[i] = fmaxf(fmaxf(sc[0][i], sc[1][i]), fmaxf(sc[2][i], sc[3][i]));
      #pragma unroll
      for (int off = 1; off < 16; off <<= 1)
        #pragma unroll
        for (int i = 0; i < 4; i++) mx[i] = fmaxf(mx[i], __shfl_xor(mx[i], off));
      float scl[4];
      #pragma unroll
      for (int i = 0; i < 4; i++){
        float mn = fmaxf(mi[i], mx[i]);
        scl[i] = __expf(mi[i] - mn);
        mi[i] = mn;
      }
      #pragma unroll
      for (int ch = 0; ch < 4; ch++)
        #pragma unroll
        for (int i = 0; i < 4; i++) sc[ch][i] = __expf(sc[ch][i] - mi[i]);
      f32x4 rs;
      #pragma unroll
      for (int i = 0; i < 4; i++)
        rs[i] = (sc[0][i] + sc[1][i]) + (sc[2][i] + sc[3][i]);
      #pragma unroll
      for (int off = 1; off < 16; off <<= 1)
        #pragma unroll
        for (int i = 0; i < 4; i++) rs[i] += __shfl_xor(rs[i], off);
      #pragma unroll
      for (int i = 0; i < 4; i++) li[i] = li[i] * scl[i] + rs[i];
      #pragma unroll
      for (int dt = 0; dt < 8; dt++)
        #pragma unroll
        for (int i = 0; i < 4; i++) accO[dt][i] *= scl[i];

      // ---- P -> LDS (bf16, swizzled byte ^= (q&7)<<4), same-wave in-order ----
      #pragma unroll
      for (int ch = 0; ch < 4; ch++)
        #pragma unroll
        for (int i = 0; i < 4; i++){
          int q = fq * 4 + i;
          int off = q * 128 + ((ch * 32 + fr * 2) ^ ((q & 7) << 4));
          *reinterpret_cast<short*>(PlB + off) = (short)f2bf(sc[ch][i]);
        }
      bf16x8 pf[2];
      #pragma unroll
      for (int c2 = 0; c2 < 2; c2++)
        pf[c2] = *reinterpret_cast<const bf16x8*>(
            PlB + fr * 128 + ((c2 * 64 + fq * 16) ^ ((fr & 7) << 4)));

      // ---- PV: O += P * V ----
      #pragma unroll
      for (int dt = 0; dt < 8; dt++)
        #pragma unroll
        for (int c2 = 0; c2 < 2; c2++){
          bf16x8 vf = *reinterpret_cast<const bf16x8*>(
              vb + (size_t)(dt * 16 + fr) * S_LEN + k0 + c2 * 32 + fq * 8);
          accO[dt] = __builtin_amdgcn_mfma_f32_16x16x32_bf16(pf[c2], vf, accO[dt], 0, 0, 0);
        }
    }

    float inv[4];
    #pragma unroll
    for (int i = 0; i < 4; i++) inv[i] = 1.f / li[i];
    #pragma unroll
    for (int dt = 0; dt < 8; dt++)
      #pragma unroll
      for (int i = 0; i < 4; i++){
        int row = qr + fq * 4 + i;
        ob[(size_t)row * DM + h * DK + dt * 16 + fr] = f2bf(accO[dt][i] * inv[i]);
      }
  }
}

extern "C" void kernel_launch(void* const* d_in, const int* in_sizes, int n_in,
                              void* d_out, int out_size, void* d_ws, size_t ws_size,
                              hipStream_t stream){
  const float* x  = (const float*)d_in[0];
  const float* wq = (const float*)d_in[1];
  const float* wk = (const float*)d_in[2];
  const float* wv = (const float*)d_in[3];
  const float* wo = (const float*)d_in[4];
  const int* pos  = (const int*)d_in[5];
  float* out = (float*)d_out;

  char* ws = (char*)d_ws;
  ushort* xb   = (ushort*)(ws);               // 16 MiB; Ob aliases after GEMM consumes xb
  ushort* Ob   = xb;
  ushort* wqkv = (ushort*)(ws + 16777216);    // 24 MiB; wo bf16 aliases after QKV GEMM
  ushort* wb   = wqkv;
  ushort* Qh   = (ushort*)(ws + 41943040);    // 16 MiB
  ushort* Kh   = (ushort*)(ws + 58720256);    // 16 MiB
  ushort* Vt   = (ushort*)(ws + 75497472);    // 16 MiB
  float2* cs   = (float2*)(ws + 92274688);    // 1 MiB

  const int M = BB * S_LEN;                    // 4096

  k_rope_table<<<(S_LEN * 64) / 256, 256, 0, stream>>>(pos, cs);
  k_f32_to_bf16<<<(M * DM / 4) / 256, 256, 0, stream>>>(x, xb, M * DM / 4);
  const int nw4 = DM * DM / 4;
  k_f32_to_bf16<<<nw4 / 256, 256, 0, stream>>>(wq, wqkv, nw4);
  k_f32_to_bf16<<<nw4 / 256, 256, 0, stream>>>(wk, wqkv + DM * DM, nw4);
  k_f32_to_bf16<<<nw4 / 256, 256, 0, stream>>>(wv, wqkv + 2 * DM * DM, nw4);

  k_gemm_qkv<<<dim3(48, M / 128), 256, 0, stream>>>(xb, wqkv, cs, Qh, Kh, Vt);

  k_attn<<<2048, 64, 0, stream>>>(Qh, Kh, Vt, Ob);

  k_f32_to_bf16<<<nw4 / 256, 256, 0, stream>>>(wo, wb, nw4);
  k_gemm_bt<<<dim3(DM / 128, M / 128), 256, 0, stream>>>(Ob, wb, out, M, DM, DM);
}

// Round 5
// 321.915 us; speedup vs baseline: 1.4411x; 1.4411x over previous
//
#include <hip/hip_runtime.h>

#define S_LEN 2048
#define DM 2048
#define NH 16
#define DK 128
#define BB 2
#define BH (BB*NH)

typedef float f32x4 __attribute__((ext_vector_type(4)));
typedef __bf16 bf16x8 __attribute__((ext_vector_type(8)));
typedef unsigned int u32;

#define AS1 __attribute__((address_space(1)))
#define AS3 __attribute__((address_space(3)))

__device__ inline void gload16(const void* g, void* l){
  __builtin_amdgcn_global_load_lds((AS1 const u32*)g, (AS3 u32*)l, 16, 0, 0);
}

__device__ inline ushort f2bf(float f){
  unsigned u = __float_as_uint(f);
  u = (u + 0x7FFFu + ((u >> 16) & 1u)) >> 16;
  return (ushort)u;
}

// ---------------- fp32 -> bf16 (vectorized) ----------------
__global__ void k_f32_to_bf16(const float* __restrict__ in, ushort* __restrict__ out, int n4){
  int i = blockIdx.x * blockDim.x + threadIdx.x;
  if (i >= n4) return;
  float4 v = reinterpret_cast<const float4*>(in)[i];
  ushort4 o;
  o.x = f2bf(v.x); o.y = f2bf(v.y); o.z = f2bf(v.z); o.w = f2bf(v.w);
  reinterpret_cast<ushort4*>(out)[i] = o;
}

// ---------------- rope cos/sin table [S][64] as float2 {cos,sin} ----------------
__global__ void k_rope_table(const int* __restrict__ pos, float2* __restrict__ cs){
  int idx = blockIdx.x * 256 + threadIdx.x;
  if (idx >= S_LEN * 64) return;
  int s = idx >> 6, i = idx & 63;
  float inv = expf(-0.14391156831212787f * (float)i);   // 10000^(-i/64)
  float f = (float)pos[s] * inv;
  cs[idx] = make_float2(cosf(f), sinf(f));
}

// ---------------- fused QKV GEMM: C = xb[4096][2048] * wqkv[6144][2048]^T ----------------
// m97 structure. Epilogue: Q/K regions -> RoPE (shfl pair) -> bf16 [bh][s][d];
// V region -> bf16 transposed [bh][d][s].
__launch_bounds__(256)
__global__ void k_gemm_qkv(const ushort* __restrict__ A, const ushort* __restrict__ Bt,
                           const float2* __restrict__ cs,
                           ushort* __restrict__ Qh, ushort* __restrict__ Kh,
                           ushort* __restrict__ Vt){
  constexpr int K = 2048;
  __shared__ short lA[128 * 32];
  __shared__ short lB[128 * 32];
  const int tid = threadIdx.x;
  const int lane = tid & 63, wid = tid >> 6;
  const int wm = wid >> 1, wn = wid & 1;
  const int bx = blockIdx.x, by = blockIdx.y;
  const int fr = lane & 15, fq = lane >> 4;

  const int sr = wid * 32 + (lane >> 2);
  const int scol = (lane & 3) * 8;
  const ushort* pa = A  + (size_t)(by * 128 + sr) * K + scol;
  const ushort* pb = Bt + (size_t)(bx * 128 + sr) * K + scol;
  char* lA0 = (char*)lA + wid * 2048;
  char* lB0 = (char*)lB + wid * 2048;

  f32x4 acc[4][4] = {};
  const int arow = wm * 64, brow = wn * 64;

  for (int kk = 0; kk < K; kk += 32){
    __syncthreads();
    gload16(pa + kk,                    lA0);
    gload16(pa + (size_t)16 * K + kk,   lA0 + 1024);
    gload16(pb + kk,                    lB0);
    gload16(pb + (size_t)16 * K + kk,   lB0 + 1024);
    __syncthreads();
    bf16x8 af[4], bfr[4];
    #pragma unroll
    for (int m = 0; m < 4; m++)
      af[m] = *reinterpret_cast<const bf16x8*>(&lA[(arow + m * 16 + fr) * 32 + fq * 8]);
    #pragma unroll
    for (int n = 0; n < 4; n++)
      bfr[n] = *reinterpret_cast<const bf16x8*>(&lB[(brow + n * 16 + fr) * 32 + fq * 8]);
    #pragma unroll
    for (int m = 0; m < 4; m++)
      #pragma unroll
      for (int n = 0; n < 4; n++)
        acc[m][n] = __builtin_amdgcn_mfma_f32_16x16x32_bf16(af[m], bfr[n], acc[m][n], 0, 0, 0);
  }

  const int rowb = by * 128 + wm * 64 + fq * 4;
  if (bx < 32){
    ushort* dst = (bx < 16) ? Qh : Kh;
    #pragma unroll
    for (int m = 0; m < 4; m++)
      #pragma unroll
      for (int n = 0; n < 4; n++){
        int col = bx * 128 + wn * 64 + n * 16 + fr;
        int cg = col & 2047;
        int hh = cg >> 7, dd = cg & 127;
        int jj = (cg >> 1) & 63;
        #pragma unroll
        for (int i = 0; i < 4; i++){
          int row = rowb + m * 16 + i;
          int s = row & (S_LEN - 1), bb = row >> 11;
          float2 c2 = cs[s * 64 + jj];
          float v = acc[m][n][i];
          float p = __shfl_xor(v, 1);
          float o = (fr & 1) ? fmaf(p, c2.y, v * c2.x) : fmaf(v, c2.x, -p * c2.y);
          dst[((size_t)(bb * NH + hh) * S_LEN + s) * DK + dd] = f2bf(o);
        }
      }
  } else {
    #pragma unroll
    for (int m = 0; m < 4; m++){
      int s0 = (rowb + m * 16) & (S_LEN - 1);
      int bb = (rowb + m * 16) >> 11;
      #pragma unroll
      for (int n = 0; n < 4; n++){
        int col = (bx - 32) * 128 + wn * 64 + n * 16 + fr;
        int hh = col >> 7, dd = col & 127;
        ushort4 o;
        o.x = f2bf(acc[m][n][0]); o.y = f2bf(acc[m][n][1]);
        o.z = f2bf(acc[m][n][2]); o.w = f2bf(acc[m][n][3]);
        *reinterpret_cast<ushort4*>(&Vt[((size_t)(bb * NH + hh) * DK + dd) * S_LEN + s0]) = o;
      }
    }
  }
}

// ---------------- GEMM: C[M][N] = A[M][K] * Bt[N][K]^T  (m97 structure, fp32 out) ----------------
__launch_bounds__(256)
__global__ void k_gemm_bt(const ushort* __restrict__ A, const ushort* __restrict__ Bt,
                          float* __restrict__ C, int M, int N, int K){
  __shared__ short lA[128 * 32];
  __shared__ short lB[128 * 32];
  const int tid = threadIdx.x;
  const int lane = tid & 63, wid = tid >> 6;
  const int wm = wid >> 1, wn = wid & 1;
  const int bx = blockIdx.x, by = blockIdx.y;
  const int fr = lane & 15, fq = lane >> 4;

  const int sr = wid * 32 + (lane >> 2);
  const int scol = (lane & 3) * 8;
  const ushort* pa = A  + (size_t)(by * 128 + sr) * K + scol;
  const ushort* pb = Bt + (size_t)(bx * 128 + sr) * K + scol;
  char* lA0 = (char*)lA + wid * 2048;
  char* lB0 = (char*)lB + wid * 2048;

  f32x4 acc[4][4] = {};
  const int arow = wm * 64, brow = wn * 64;

  for (int kk = 0; kk < K; kk += 32){
    __syncthreads();
    gload16(pa + kk,                    lA0);
    gload16(pa + (size_t)16 * K + kk,   lA0 + 1024);
    gload16(pb + kk,                    lB0);
    gload16(pb + (size_t)16 * K + kk,   lB0 + 1024);
    __syncthreads();
    bf16x8 af[4], bfr[4];
    #pragma unroll
    for (int m = 0; m < 4; m++)
      af[m] = *reinterpret_cast<const bf16x8*>(&lA[(arow + m * 16 + fr) * 32 + fq * 8]);
    #pragma unroll
    for (int n = 0; n < 4; n++)
      bfr[n] = *reinterpret_cast<const bf16x8*>(&lB[(brow + n * 16 + fr) * 32 + fq * 8]);
    #pragma unroll
    for (int m = 0; m < 4; m++)
      #pragma unroll
      for (int n = 0; n < 4; n++)
        acc[m][n] = __builtin_amdgcn_mfma_f32_16x16x32_bf16(af[m], bfr[n], acc[m][n], 0, 0, 0);
  }
  const int orow = by * 128 + wm * 64 + fq * 4;
  const int ocol = bx * 128 + wn * 64 + fr;
  #pragma unroll
  for (int m = 0; m < 4; m++)
    #pragma unroll
    for (int n = 0; n < 4; n++)
      #pragma unroll
      for (int i = 0; i < 4; i++)
        C[(size_t)(orow + m * 16 + i) * N + ocol + n * 16] = acc[m][n][i];
}

// ---------------- causal flash attention: 4-wave blocks, LDS-shared K/V, paired chunks ----------------
// 512 blocks x 256 thr. Block (pid,bh): chunk jA=31-pid then jB=pid (64 q-rows each).
// Per-block work = (jA+1)+(jB+1) = 33 kv-tiles, uniform. Wave w owns 16 rows of the chunk.
// K[64][128]+V[128][64] double-buffered in LDS via swizzled global_load_lds; prefetch next tile.
__launch_bounds__(256)
__global__ void k_attn(const ushort* __restrict__ Q, const ushort* __restrict__ K,
                       const ushort* __restrict__ Vt, ushort* __restrict__ O){
  __shared__ short Kt[2][64 * 128];   // [kv][d] swizzled (16KB each)
  __shared__ short Vl[2][128 * 64];   // [d][kv] swizzled (16KB each)
  __shared__ short Pl[4][16 * 64];    // per-wave P [q][kv] swizzled (2KB each)
  const int tid = threadIdx.x, lane = tid & 63, wid = tid >> 6;
  const int bid = blockIdx.x;
  const int pid = bid >> 5;           // 0..15
  const int bh = bid & 31;
  const int b = bh >> 4, h = bh & 15;
  const int fr = lane & 15, fq = lane >> 4;
  const int swz = (fr & 7) << 4;

  const ushort* kb = K  + (size_t)bh * S_LEN * DK;
  const ushort* vb = Vt + (size_t)bh * DK * S_LEN;
  char* PlB = (char*)(&Pl[wid][0]);
  const float scale = 0.08838834764831845f;   // 1/sqrt(128)
  ushort* ob = O + (size_t)b * S_LEN * DM;

  // per-lane swizzled staging source offsets (4 instrs/wave for K, 4 for V)
  int kro[4], kco[4], vro[4], vco[4];
  #pragma unroll
  for (int jj = 0; jj < 4; jj++){
    int ins = wid * 4 + jj;
    kro[jj] = ins * 4 + (lane >> 4);
    kco[jj] = 8 * ((lane & 15) ^ (kro[jj] & 7));
    vro[jj] = ins * 8 + (lane >> 3);
    vco[jj] = 8 * ((lane & 7) ^ (vro[jj] & 7));
  }

  #pragma unroll 1
  for (int half = 0; half < 2; half++){
    const int j = half ? pid : 31 - pid;
    const int qr = j * 64 + wid * 16;
    const int nt = j + 1;

    bf16x8 qf[4];
    #pragma unroll
    for (int c = 0; c < 4; c++)
      qf[c] = *reinterpret_cast<const bf16x8*>(
          Q + ((size_t)bh * S_LEN + qr + fr) * DK + c * 32 + fq * 8);

    float mi[4], li[4];
    #pragma unroll
    for (int i = 0; i < 4; i++){ mi[i] = -1e30f; li[i] = 0.f; }
    f32x4 accO[8] = {};

    // protect buffers from previous chunk's readers, then stage tile 0
    __syncthreads();
    {
      char* kd = (char*)Kt + (wid * 4) * 1024;
      char* vd = (char*)Vl + (wid * 4) * 1024;
      #pragma unroll
      for (int jj = 0; jj < 4; jj++){
        gload16(kb + (size_t)kro[jj] * DK + kco[jj],      kd + jj * 1024);
        gload16(vb + (size_t)vro[jj] * S_LEN + vco[jj],   vd + jj * 1024);
      }
    }
    __syncthreads();

    #pragma unroll 1
    for (int kt = 0; kt < nt; kt++){
      const int k0 = kt * 64;
      const int cur = kt & 1;
      if (kt + 1 < nt){
        const int k1 = k0 + 64;
        char* kd = (char*)Kt + (cur ^ 1) * 16384 + (wid * 4) * 1024;
        char* vd = (char*)Vl + (cur ^ 1) * 16384 + (wid * 4) * 1024;
        #pragma unroll
        for (int jj = 0; jj < 4; jj++){
          gload16(kb + (size_t)(k1 + kro[jj]) * DK + kco[jj],    kd + jj * 1024);
          gload16(vb + (size_t)vro[jj] * S_LEN + k1 + vco[jj],   vd + jj * 1024);
        }
      }
      const char* KtB = (const char*)Kt + cur * 16384;
      const char* VlB = (const char*)Vl + cur * 16384;

      // ---- QK^T: S[16 q][64 kv] ----
      f32x4 sc[4] = {};
      #pragma unroll
      for (int c = 0; c < 4; c++){
        bf16x8 kf[4];
        #pragma unroll
        for (int ch = 0; ch < 4; ch++)
          kf[ch] = *reinterpret_cast<const bf16x8*>(
              KtB + (ch * 16 + fr) * 256 + ((c * 64 + fq * 16) ^ swz));
        #pragma unroll
        for (int ch = 0; ch < 4; ch++)
          sc[ch] = __builtin_amdgcn_mfma_f32_16x16x32_bf16(qf[c], kf[ch], sc[ch], 0, 0, 0);
      }

      // ---- scale + causal mask (last tile only) + online softmax ----
      const bool needmask = (kt == nt - 1);
      #pragma unroll
      for (int ch = 0; ch < 4; ch++)
        #pragma unroll
        for (int i = 0; i < 4; i++){
          float v = sc[ch][i] * scale;
          if (needmask && (k0 + ch * 16 + fr > qr + fq * 4 + i)) v = -1e30f;
          sc[ch][i] = v;
        }
      f32x4 mx;
      #pragma unroll
      for (int i = 0; i < 4; i++)
        mx[i] = fmaxf(fmaxf(sc[0][i], sc[1][i]), fmaxf(sc[2][i], sc[3][i]));
      #pragma unroll
      for (int off = 1; off < 16; off <<= 1)
        #pragma unroll
        for (int i = 0; i < 4; i++) mx[i] = fmaxf(mx[i], __shfl_xor(mx[i], off));
      float scl[4];
      #pragma unroll
      for (int i = 0; i < 4; i++){
        float mn = fmaxf(mi[i], mx[i]);
        scl[i] = __expf(mi[i] - mn);
        mi[i] = mn;
      }
      #pragma unroll
      for (int ch = 0; ch < 4; ch++)
        #pragma unroll
        for (int i = 0; i < 4; i++) sc[ch][i] = __expf(sc[ch][i] - mi[i]);
      f32x4 rs;
      #pragma unroll
      for (int i = 0; i < 4; i++)
        rs[i] = (sc[0][i] + sc[1][i]) + (sc[2][i] + sc[3][i]);
      #pragma unroll
      for (int off = 1; off < 16; off <<= 1)
        #pragma unroll
        for (int i = 0; i < 4; i++) rs[i] += __shfl_xor(rs[i], off);
      #pragma unroll
      for (int i = 0; i < 4; i++) li[i] = li[i] * scl[i] + rs[i];
      #pragma unroll
      for (int dt = 0; dt < 8; dt++)
        #pragma unroll
        for (int i = 0; i < 4; i++) accO[dt][i] *= scl[i];

      // ---- P -> LDS (bf16, swizzled), same-wave in-order ----
      #pragma unroll
      for (int ch = 0; ch < 4; ch++)
        #pragma unroll
        for (int i = 0; i < 4; i++){
          int q = fq * 4 + i;
          int off = q * 128 + ((ch * 32 + fr * 2) ^ ((q & 7) << 4));
          *reinterpret_cast<short*>(PlB + off) = (short)f2bf(sc[ch][i]);
        }
      bf16x8 pf[2];
      #pragma unroll
      for (int c2 = 0; c2 < 2; c2++)
        pf[c2] = *reinterpret_cast<const bf16x8*>(
            PlB + fr * 128 + ((c2 * 64 + fq * 16) ^ swz));

      // ---- PV: O += P * V ----
      #pragma unroll
      for (int dt = 0; dt < 8; dt++)
        #pragma unroll
        for (int c2 = 0; c2 < 2; c2++){
          bf16x8 vf = *reinterpret_cast<const bf16x8*>(
              VlB + (dt * 16 + fr) * 128 + ((c2 * 64 + fq * 16) ^ swz));
          accO[dt] = __builtin_amdgcn_mfma_f32_16x16x32_bf16(pf[c2], vf, accO[dt], 0, 0, 0);
        }
      __syncthreads();
    }

    float inv[4];
    #pragma unroll
    for (int i = 0; i < 4; i++) inv[i] = 1.f / li[i];
    #pragma unroll
    for (int dt = 0; dt < 8; dt++)
      #pragma unroll
      for (int i = 0; i < 4; i++){
        int row = qr + fq * 4 + i;
        ob[(size_t)row * DM + h * DK + dt * 16 + fr] = f2bf(accO[dt][i] * inv[i]);
      }
  }
}

extern "C" void kernel_launch(void* const* d_in, const int* in_sizes, int n_in,
                              void* d_out, int out_size, void* d_ws, size_t ws_size,
                              hipStream_t stream){
  const float* x  = (const float*)d_in[0];
  const float* wq = (const float*)d_in[1];
  const float* wk = (const float*)d_in[2];
  const float* wv = (const float*)d_in[3];
  const float* wo = (const float*)d_in[4];
  const int* pos  = (const int*)d_in[5];
  float* out = (float*)d_out;

  char* ws = (char*)d_ws;
  ushort* xb   = (ushort*)(ws);               // 16 MiB; Ob aliases after GEMM consumes xb
  ushort* Ob   = xb;
  ushort* wqkv = (ushort*)(ws + 16777216);    // 24 MiB; wo bf16 aliases after QKV GEMM
  ushort* wb   = wqkv;
  ushort* Qh   = (ushort*)(ws + 41943040);    // 16 MiB
  ushort* Kh   = (ushort*)(ws + 58720256);    // 16 MiB
  ushort* Vt   = (ushort*)(ws + 75497472);    // 16 MiB
  float2* cs   = (float2*)(ws + 92274688);    // 1 MiB

  const int M = BB * S_LEN;                    // 4096

  k_rope_table<<<(S_LEN * 64) / 256, 256, 0, stream>>>(pos, cs);
  k_f32_to_bf16<<<(M * DM / 4) / 256, 256, 0, stream>>>(x, xb, M * DM / 4);
  const int nw4 = DM * DM / 4;
  k_f32_to_bf16<<<nw4 / 256, 256, 0, stream>>>(wq, wqkv, nw4);
  k_f32_to_bf16<<<nw4 / 256, 256, 0, stream>>>(wk, wqkv + DM * DM, nw4);
  k_f32_to_bf16<<<nw4 / 256, 256, 0, stream>>>(wv, wqkv + 2 * DM * DM, nw4);

  k_gemm_qkv<<<dim3(48, M / 128), 256, 0, stream>>>(xb, wqkv, cs, Qh, Kh, Vt);

  k_attn<<<512, 256, 0, stream>>>(Qh, Kh, Vt, Ob);

  k_f32_to_bf16<<<nw4 / 256, 256, 0, stream>>>(wo, wb, nw4);
  k_gemm_bt<<<dim3(DM / 128, M / 128), 256, 0, stream>>>(Ob, wb, out, M, DM, DM);
}

// Round 6
// 315.811 us; speedup vs baseline: 1.4690x; 1.0193x over previous
//
#include <hip/hip_runtime.h>

#define S_LEN 2048
#define DM 2048
#define NH 16
#define DK 128
#define BB 2
#define BH (BB*NH)
#define GK 2048

typedef float f32x4 __attribute__((ext_vector_type(4)));
typedef __bf16 bf16x8 __attribute__((ext_vector_type(8)));
typedef unsigned int u32;

#define AS1 __attribute__((address_space(1)))
#define AS3 __attribute__((address_space(3)))

__device__ inline void gload16(const void* g, void* l){
  __builtin_amdgcn_global_load_lds((AS1 const u32*)g, (AS3 u32*)l, 16, 0, 0);
}

__device__ inline ushort f2bf(float f){
  unsigned u = __float_as_uint(f);
  u = (u + 0x7FFFu + ((u >> 16) & 1u)) >> 16;
  return (ushort)u;
}

// ---------------- fp32 -> bf16 (vectorized) ----------------
__global__ void k_f32_to_bf16(const float* __restrict__ in, ushort* __restrict__ out, int n4){
  int i = blockIdx.x * blockDim.x + threadIdx.x;
  if (i >= n4) return;
  float4 v = reinterpret_cast<const float4*>(in)[i];
  ushort4 o;
  o.x = f2bf(v.x); o.y = f2bf(v.y); o.z = f2bf(v.z); o.w = f2bf(v.w);
  reinterpret_cast<ushort4*>(out)[i] = o;
}

// ---------------- rope cos/sin table [S][64] as float2 {cos,sin} ----------------
__global__ void k_rope_table(const int* __restrict__ pos, float2* __restrict__ cs){
  int idx = blockIdx.x * 256 + threadIdx.x;
  if (idx >= S_LEN * 64) return;
  int s = idx >> 6, i = idx & 63;
  float inv = expf(-0.14391156831212787f * (float)i);   // 10000^(-i/64)
  float f = (float)pos[s] * inv;
  cs[idx] = make_float2(cosf(f), sinf(f));
}

// ================= fused QKV GEMM: 256x256 tile, BK=64, 8 waves, 8-phase =================
// LDS ring: 8 half-slots of 16KB = [256 rows][32 k] bf16; slot = (ktile&1)*4 + {0:Ak0,1:Bk0,2:Ak1,3:Bk1}.
// Per phase: ds_read quadrant + stage 1 half-slot (2x global_load_lds w16, source pre-swizzled);
// counted vmcnt(6) at even phases only; raw s_barrier; setprio around 16-MFMA cluster.
// Epilogue: Q/K -> RoPE (shfl pair) bf16 [bh][s][d]; V -> bf16 transposed [bh][d][s].
#define SBAR() do{ __builtin_amdgcn_s_barrier(); __builtin_amdgcn_sched_barrier(0); }while(0)
#define VMC(n) asm volatile("s_waitcnt vmcnt(" #n ")" ::: "memory")

#define STG(slot, srcp, tks, khh) do{ \
  const ushort* _s = (srcp) + (tks)*64 + (khh)*32; \
  gload16(_s,                    lds + (slot)*8192 + wid*512); \
  gload16(_s + (size_t)128*GK,   lds + (slot)*8192 + 4096 + wid*512); \
}while(0)

#define RD_A(slot, mh) do{ \
  af[0] = *reinterpret_cast<const bf16x8*>(ldsc + (slot)*16384 + wm*8192 + ((mh)*4+0)*1024 + frA); \
  af[1] = *reinterpret_cast<const bf16x8*>(ldsc + (slot)*16384 + wm*8192 + ((mh)*4+1)*1024 + frA); \
  af[2] = *reinterpret_cast<const bf16x8*>(ldsc + (slot)*16384 + wm*8192 + ((mh)*4+2)*1024 + frA); \
  af[3] = *reinterpret_cast<const bf16x8*>(ldsc + (slot)*16384 + wm*8192 + ((mh)*4+3)*1024 + frA); \
}while(0)

#define RD_B(slot) do{ \
  bfr[0] = *reinterpret_cast<const bf16x8*>(ldsc + (slot)*16384 + wn*4096 + 0*1024 + frA); \
  bfr[1] = *reinterpret_cast<const bf16x8*>(ldsc + (slot)*16384 + wn*4096 + 1*1024 + frA); \
  bfr[2] = *reinterpret_cast<const bf16x8*>(ldsc + (slot)*16384 + wn*4096 + 2*1024 + frA); \
  bfr[3] = *reinterpret_cast<const bf16x8*>(ldsc + (slot)*16384 + wn*4096 + 3*1024 + frA); \
}while(0)

#define MM(mh) do{ \
  __builtin_amdgcn_s_setprio(1); \
  _Pragma("unroll") \
  for (int mf2 = 0; mf2 < 4; mf2++) \
    _Pragma("unroll") \
    for (int nf = 0; nf < 4; nf++) \
      acc[(mh)*4+mf2][nf] = __builtin_amdgcn_mfma_f32_16x16x32_bf16(af[mf2], bfr[nf], acc[(mh)*4+mf2][nf], 0, 0, 0); \
  __builtin_amdgcn_s_setprio(0); \
}while(0)

__launch_bounds__(512, 2)
__global__ void k_gemm_qkv8(const ushort* __restrict__ A, const ushort* __restrict__ Bt,
                            const float2* __restrict__ cs,
                            ushort* __restrict__ Qh, ushort* __restrict__ Kh,
                            ushort* __restrict__ Vt){
  __shared__ short lds[65536];   // 128 KiB: 8 half-slots x 16 KB
  const int tid = threadIdx.x, lane = tid & 63, wid = tid >> 6;
  const int wm = wid >> 2, wn = wid & 3;
  const int fr = lane & 15, fq = lane >> 4;

  // XCD-bijective block swizzle (384 = 8*48)
  const int bid = blockIdx.x;
  const int b2 = (bid & 7) * 48 + (bid >> 3);
  const int by = b2 / 24, bx = b2 % 24;

  // staging source (pre-swizzled k-unit: ku ^ (row&3)); row = j*128 + wid*16 + lane>>2
  const int rbase = wid * 16 + (lane >> 2);
  const int kup = ((lane & 3) ^ ((lane >> 2) & 3)) * 8;
  const ushort* pa = A  + (size_t)(by * 256 + rbase) * GK + kup;
  const ushort* pb = Bt + (size_t)(bx * 256 + rbase) * GK + kup;

  // ds_read per-lane byte offset within a 16-row frag block (swizzled to match)
  const char* ldsc = (const char*)lds;
  const int frA = fr * 64 + ((fq * 16) ^ ((fr & 3) << 4));

  f32x4 acc[8][4] = {};
  bf16x8 af[4], bfr[4];

  // prologue: stage K-tile 0 (4 halves) + K-tile 1 (h0,h1) = 12 loads
  STG(0, pa, 0, 0); STG(1, pb, 0, 0); STG(2, pa, 0, 1); STG(3, pb, 0, 1);
  STG(4, pa, 1, 0); STG(5, pb, 1, 0);
  VMC(8);
  SBAR();

  #pragma unroll 1
  for (int it = 0; it < 16; ++it){
    const int tb  = 2 * it + 1;
    const int tn  = (2 * it + 2 < 32) ? 2 * it + 2 : 31;   // clamp keeps vmcnt counts uniform
    const int tn1 = (2 * it + 3 < 32) ? 2 * it + 3 : 31;
    // ph1: compute ta kh0 mh0
    RD_A(0, 0); RD_B(1); STG(6, pa, tb, 1);           SBAR(); MM(0); SBAR();
    // ph2: ta kh0 mh1
    RD_A(0, 1);          STG(7, pb, tb, 1);  VMC(6);  SBAR(); MM(1); SBAR();
    // ph3: ta kh1 mh0
    RD_A(2, 0); RD_B(3); STG(0, pa, tn, 0);           SBAR(); MM(0); SBAR();
    // ph4: ta kh1 mh1
    RD_A(2, 1);          STG(1, pb, tn, 0);  VMC(6);  SBAR(); MM(1); SBAR();
    // ph5: tb kh0 mh0
    RD_A(4, 0); RD_B(5); STG(2, pa, tn, 1);           SBAR(); MM(0); SBAR();
    // ph6: tb kh0 mh1
    RD_A(4, 1);          STG(3, pb, tn, 1);  VMC(6);  SBAR(); MM(1); SBAR();
    // ph7: tb kh1 mh0
    RD_A(6, 0); RD_B(7); STG(4, pa, tn1, 0);          SBAR(); MM(0); SBAR();
    // ph8: tb kh1 mh1
    RD_A(6, 1);          STG(5, pb, tn1, 0); VMC(6);  SBAR(); MM(1); SBAR();
  }

  // ---------------- epilogue ----------------
  const int rowb = by * 256 + wm * 128 + fq * 4;
  if (bx < 16){
    ushort* dst = (bx < 8) ? Qh : Kh;
    #pragma unroll
    for (int mf = 0; mf < 8; mf++)
      #pragma unroll
      for (int nf = 0; nf < 4; nf++){
        int col = bx * 256 + wn * 64 + nf * 16 + fr;
        int cg = col & 2047;
        int hh = cg >> 7, dd = cg & 127, jj = (cg >> 1) & 63;
        #pragma unroll
        for (int i = 0; i < 4; i++){
          int row = rowb + mf * 16 + i;
          int s = row & (S_LEN - 1), bb = row >> 11;
          float2 c2 = cs[s * 64 + jj];
          float v = acc[mf][nf][i];
          float p = __shfl_xor(v, 1);
          float o = (fr & 1) ? fmaf(p, c2.y, v * c2.x) : fmaf(v, c2.x, -p * c2.y);
          dst[((size_t)(bb * NH + hh) * S_LEN + s) * DK + dd] = f2bf(o);
        }
      }
  } else {
    #pragma unroll
    for (int mf = 0; mf < 8; mf++){
      int row0 = rowb + mf * 16;
      int s0 = row0 & (S_LEN - 1), bb = row0 >> 11;
      #pragma unroll
      for (int nf = 0; nf < 4; nf++){
        int col = (bx - 16) * 256 + wn * 64 + nf * 16 + fr;
        int hh = col >> 7, dd = col & 127;
        ushort4 o;
        o.x = f2bf(acc[mf][nf][0]); o.y = f2bf(acc[mf][nf][1]);
        o.z = f2bf(acc[mf][nf][2]); o.w = f2bf(acc[mf][nf][3]);
        *reinterpret_cast<ushort4*>(&Vt[((size_t)(bb * NH + hh) * DK + dd) * S_LEN + s0]) = o;
      }
    }
  }
}

// ---------------- GEMM: C[M][N] = A[M][K] * Bt[N][K]^T  (m97 structure, fp32 out) ----------------
__launch_bounds__(256)
__global__ void k_gemm_bt(const ushort* __restrict__ A, const ushort* __restrict__ Bt,
                          float* __restrict__ C, int M, int N, int K){
  __shared__ short lA[128 * 32];
  __shared__ short lB[128 * 32];
  const int tid = threadIdx.x;
  const int lane = tid & 63, wid = tid >> 6;
  const int wm = wid >> 1, wn = wid & 1;
  const int bx = blockIdx.x, by = blockIdx.y;
  const int fr = lane & 15, fq = lane >> 4;

  const int sr = wid * 32 + (lane >> 2);
  const int scol = (lane & 3) * 8;
  const ushort* pa = A  + (size_t)(by * 128 + sr) * K + scol;
  const ushort* pb = Bt + (size_t)(bx * 128 + sr) * K + scol;
  char* lA0 = (char*)lA + wid * 2048;
  char* lB0 = (char*)lB + wid * 2048;

  f32x4 acc[4][4] = {};
  const int arow = wm * 64, brow = wn * 64;

  for (int kk = 0; kk < K; kk += 32){
    __syncthreads();
    gload16(pa + kk,                    lA0);
    gload16(pa + (size_t)16 * K + kk,   lA0 + 1024);
    gload16(pb + kk,                    lB0);
    gload16(pb + (size_t)16 * K + kk,   lB0 + 1024);
    __syncthreads();
    bf16x8 af[4], bfr[4];
    #pragma unroll
    for (int m = 0; m < 4; m++)
      af[m] = *reinterpret_cast<const bf16x8*>(&lA[(arow + m * 16 + fr) * 32 + fq * 8]);
    #pragma unroll
    for (int n = 0; n < 4; n++)
      bfr[n] = *reinterpret_cast<const bf16x8*>(&lB[(brow + n * 16 + fr) * 32 + fq * 8]);
    #pragma unroll
    for (int m = 0; m < 4; m++)
      #pragma unroll
      for (int n = 0; n < 4; n++)
        acc[m][n] = __builtin_amdgcn_mfma_f32_16x16x32_bf16(af[m], bfr[n], acc[m][n], 0, 0, 0);
  }
  const int orow = by * 128 + wm * 64 + fq * 4;
  const int ocol = bx * 128 + wn * 64 + fr;
  #pragma unroll
  for (int m = 0; m < 4; m++)
    #pragma unroll
    for (int n = 0; n < 4; n++)
      #pragma unroll
      for (int i = 0; i < 4; i++)
        C[(size_t)(orow + m * 16 + i) * N + ocol + n * 16] = acc[m][n][i];
}

// ---------------- causal flash attention: 4-wave blocks, LDS-shared K/V, paired chunks ----------------
__launch_bounds__(256)
__global__ void k_attn(const ushort* __restrict__ Q, const ushort* __restrict__ K,
                       const ushort* __restrict__ Vt, ushort* __restrict__ O){
  __shared__ short Kt[2][64 * 128];   // [kv][d] swizzled (16KB each)
  __shared__ short Vl[2][128 * 64];   // [d][kv] swizzled (16KB each)
  __shared__ short Pl[4][16 * 64];    // per-wave P [q][kv] swizzled (2KB each)
  const int tid = threadIdx.x, lane = tid & 63, wid = tid >> 6;
  const int bid = blockIdx.x;
  const int pid = bid >> 5;           // 0..15
  const int bh = bid & 31;
  const int b = bh >> 4, h = bh & 15;
  const int fr = lane & 15, fq = lane >> 4;
  const int swz = (fr & 7) << 4;

  const ushort* kb = K  + (size_t)bh * S_LEN * DK;
  const ushort* vb = Vt + (size_t)bh * DK * S_LEN;
  char* PlB = (char*)(&Pl[wid][0]);
  const float scale = 0.08838834764831845f;   // 1/sqrt(128)
  ushort* ob = O + (size_t)b * S_LEN * DM;

  int kro[4], kco[4], vro[4], vco[4];
  #pragma unroll
  for (int jj = 0; jj < 4; jj++){
    int ins = wid * 4 + jj;
    kro[jj] = ins * 4 + (lane >> 4);
    kco[jj] = 8 * ((lane & 15) ^ (kro[jj] & 7));
    vro[jj] = ins * 8 + (lane >> 3);
    vco[jj] = 8 * ((lane & 7) ^ (vro[jj] & 7));
  }

  #pragma unroll 1
  for (int half = 0; half < 2; half++){
    const int j = half ? pid : 31 - pid;
    const int qr = j * 64 + wid * 16;
    const int nt = j + 1;

    bf16x8 qf[4];
    #pragma unroll
    for (int c = 0; c < 4; c++)
      qf[c] = *reinterpret_cast<const bf16x8*>(
          Q + ((size_t)bh * S_LEN + qr + fr) * DK + c * 32 + fq * 8);

    float mi[4], li[4];
    #pragma unroll
    for (int i = 0; i < 4; i++){ mi[i] = -1e30f; li[i] = 0.f; }
    f32x4 accO[8] = {};

    __syncthreads();
    {
      char* kd = (char*)Kt + (wid * 4) * 1024;
      char* vd = (char*)Vl + (wid * 4) * 1024;
      #pragma unroll
      for (int jj = 0; jj < 4; jj++){
        gload16(kb + (size_t)kro[jj] * DK + kco[jj],      kd + jj * 1024);
        gload16(vb + (size_t)vro[jj] * S_LEN + vco[jj],   vd + jj * 1024);
      }
    }
    __syncthreads();

    #pragma unroll 1
    for (int kt = 0; kt < nt; kt++){
      const int k0 = kt * 64;
      const int cur = kt & 1;
      if (kt + 1 < nt){
        const int k1 = k0 + 64;
        char* kd = (char*)Kt + (cur ^ 1) * 16384 + (wid * 4) * 1024;
        char* vd = (char*)Vl + (cur ^ 1) * 16384 + (wid * 4) * 1024;
        #pragma unroll
        for (int jj = 0; jj < 4; jj++){
          gload16(kb + (size_t)(k1 + kro[jj]) * DK + kco[jj],    kd + jj * 1024);
          gload16(vb + (size_t)vro[jj] * S_LEN + k1 + vco[jj],   vd + jj * 1024);
        }
      }
      const char* KtB = (const char*)Kt + cur * 16384;
      const char* VlB = (const char*)Vl + cur * 16384;

      f32x4 sc[4] = {};
      #pragma unroll
      for (int c = 0; c < 4; c++){
        bf16x8 kf[4];
        #pragma unroll
        for (int ch = 0; ch < 4; ch++)
          kf[ch] = *reinterpret_cast<const bf16x8*>(
              KtB + (ch * 16 + fr) * 256 + ((c * 64 + fq * 16) ^ swz));
        #pragma unroll
        for (int ch = 0; ch < 4; ch++)
          sc[ch] = __builtin_amdgcn_mfma_f32_16x16x32_bf16(qf[c], kf[ch], sc[ch], 0, 0, 0);
      }

      const bool needmask = (kt == nt - 1);
      #pragma unroll
      for (int ch = 0; ch < 4; ch++)
        #pragma unroll
        for (int i = 0; i < 4; i++){
          float v = sc[ch][i] * scale;
          if (needmask && (k0 + ch * 16 + fr > qr + fq * 4 + i)) v = -1e30f;
          sc[ch][i] = v;
        }
      f32x4 mx;
      #pragma unroll
      for (int i = 0; i < 4; i++)
        mx[i] = fmaxf(fmaxf(sc[0][i], sc[1][i]), fmaxf(sc[2][i], sc[3][i]));
      #pragma unroll
      for (int off = 1; off < 16; off <<= 1)
        #pragma unroll
        for (int i = 0; i < 4; i++) mx[i] = fmaxf(mx[i], __shfl_xor(mx[i], off));
      float scl[4];
      #pragma unroll
      for (int i = 0; i < 4; i++){
        float mn = fmaxf(mi[i], mx[i]);
        scl[i] = __expf(mi[i] - mn);
        mi[i] = mn;
      }
      #pragma unroll
      for (int ch = 0; ch < 4; ch++)
        #pragma unroll
        for (int i = 0; i < 4; i++) sc[ch][i] = __expf(sc[ch][i] - mi[i]);
      f32x4 rs;
      #pragma unroll
      for (int i = 0; i < 4; i++)
        rs[i] = (sc[0][i] + sc[1][i]) + (sc[2][i] + sc[3][i]);
      #pragma unroll
      for (int off = 1; off < 16; off <<= 1)
        #pragma unroll
        for (int i = 0; i < 4; i++) rs[i] += __shfl_xor(rs[i], off);
      #pragma unroll
      for (int i = 0; i < 4; i++) li[i] = li[i] * scl[i] + rs[i];
      #pragma unroll
      for (int dt = 0; dt < 8; dt++)
        #pragma unroll
        for (int i = 0; i < 4; i++) accO[dt][i] *= scl[i];

      #pragma unroll
      for (int ch = 0; ch < 4; ch++)
        #pragma unroll
        for (int i = 0; i < 4; i++){
          int q = fq * 4 + i;
          int off = q * 128 + ((ch * 32 + fr * 2) ^ ((q & 7) << 4));
          *reinterpret_cast<short*>(PlB + off) = (short)f2bf(sc[ch][i]);
        }
      bf16x8 pf[2];
      #pragma unroll
      for (int c2 = 0; c2 < 2; c2++)
        pf[c2] = *reinterpret_cast<const bf16x8*>(
            PlB + fr * 128 + ((c2 * 64 + fq * 16) ^ swz));

      #pragma unroll
      for (int dt = 0; dt < 8; dt++)
        #pragma unroll
        for (int c2 = 0; c2 < 2; c2++){
          bf16x8 vf = *reinterpret_cast<const bf16x8*>(
              VlB + (dt * 16 + fr) * 128 + ((c2 * 64 + fq * 16) ^ swz));
          accO[dt] = __builtin_amdgcn_mfma_f32_16x16x32_bf16(pf[c2], vf, accO[dt], 0, 0, 0);
        }
      __syncthreads();
    }

    float inv[4];
    #pragma unroll
    for (int i = 0; i < 4; i++) inv[i] = 1.f / li[i];
    #pragma unroll
    for (int dt = 0; dt < 8; dt++)
      #pragma unroll
      for (int i = 0; i < 4; i++){
        int row = qr + fq * 4 + i;
        ob[(size_t)row * DM + h * DK + dt * 16 + fr] = f2bf(accO[dt][i] * inv[i]);
      }
  }
}

extern "C" void kernel_launch(void* const* d_in, const int* in_sizes, int n_in,
                              void* d_out, int out_size, void* d_ws, size_t ws_size,
                              hipStream_t stream){
  const float* x  = (const float*)d_in[0];
  const float* wq = (const float*)d_in[1];
  const float* wk = (const float*)d_in[2];
  const float* wv = (const float*)d_in[3];
  const float* wo = (const float*)d_in[4];
  const int* pos  = (const int*)d_in[5];
  float* out = (float*)d_out;

  char* ws = (char*)d_ws;
  ushort* xb   = (ushort*)(ws);               // 16 MiB; Ob aliases after GEMM consumes xb
  ushort* Ob   = xb;
  ushort* wqkv = (ushort*)(ws + 16777216);    // 24 MiB; wo bf16 aliases after QKV GEMM
  ushort* wb   = wqkv;
  ushort* Qh   = (ushort*)(ws + 41943040);    // 16 MiB
  ushort* Kh   = (ushort*)(ws + 58720256);    // 16 MiB
  ushort* Vt   = (ushort*)(ws + 75497472);    // 16 MiB
  float2* cs   = (float2*)(ws + 92274688);    // 1 MiB

  const int M = BB * S_LEN;                    // 4096

  k_rope_table<<<(S_LEN * 64) / 256, 256, 0, stream>>>(pos, cs);
  k_f32_to_bf16<<<(M * DM / 4) / 256, 256, 0, stream>>>(x, xb, M * DM / 4);
  const int nw4 = DM * DM / 4;
  k_f32_to_bf16<<<nw4 / 256, 256, 0, stream>>>(wq, wqkv, nw4);
  k_f32_to_bf16<<<nw4 / 256, 256, 0, stream>>>(wk, wqkv + DM * DM, nw4);
  k_f32_to_bf16<<<nw4 / 256, 256, 0, stream>>>(wv, wqkv + 2 * DM * DM, nw4);

  k_gemm_qkv8<<<384, 512, 0, stream>>>(xb, wqkv, cs, Qh, Kh, Vt);

  k_attn<<<512, 256, 0, stream>>>(Qh, Kh, Vt, Ob);

  k_f32_to_bf16<<<nw4 / 256, 256, 0, stream>>>(wo, wb, nw4);
  k_gemm_bt<<<dim3(DM / 128, M / 128), 256, 0, stream>>>(Ob, wb, out, M, DM, DM);
}

// Round 7
// 314.501 us; speedup vs baseline: 1.4751x; 1.0042x over previous
//
#include <hip/hip_runtime.h>

#define S_LEN 2048
#define DM 2048
#define NH 16
#define DK 128
#define BB 2
#define BH (BB*NH)
#define GK 2048

typedef float f32x4 __attribute__((ext_vector_type(4)));
typedef __bf16 bf16x8 __attribute__((ext_vector_type(8)));
typedef unsigned int u32;

#define AS1 __attribute__((address_space(1)))
#define AS3 __attribute__((address_space(3)))

__device__ inline void gload16(const void* g, void* l){
  __builtin_amdgcn_global_load_lds((AS1 const u32*)g, (AS3 u32*)l, 16, 0, 0);
}

__device__ inline ushort f2bf(float f){
  unsigned u = __float_as_uint(f);
  u = (u + 0x7FFFu + ((u >> 16) & 1u)) >> 16;
  return (ushort)u;
}

// ---------------- fp32 -> bf16 (vectorized) ----------------
__global__ void k_f32_to_bf16(const float* __restrict__ in, ushort* __restrict__ out, int n4){
  int i = blockIdx.x * blockDim.x + threadIdx.x;
  if (i >= n4) return;
  float4 v = reinterpret_cast<const float4*>(in)[i];
  ushort4 o;
  o.x = f2bf(v.x); o.y = f2bf(v.y); o.z = f2bf(v.z); o.w = f2bf(v.w);
  reinterpret_cast<ushort4*>(out)[i] = o;
}

// ---------------- rope cos/sin table [S][64] as float2 {cos,sin} ----------------
__global__ void k_rope_table(const int* __restrict__ pos, float2* __restrict__ cs){
  int idx = blockIdx.x * 256 + threadIdx.x;
  if (idx >= S_LEN * 64) return;
  int s = idx >> 6, i = idx & 63;
  float inv = expf(-0.14391156831212787f * (float)i);   // 10000^(-i/64)
  float f = (float)pos[s] * inv;
  cs[idx] = make_float2(cosf(f), sinf(f));
}

// ================= fused QKV GEMM: 256x256 tile, BK=64, 8 waves, 8-phase =================
// LDS ring: 8 half-slots of 16KB = [256 rows][32 k] bf16; slot = (ktile&1)*4 + {0:Ak0,1:Bk0,2:Ak1,3:Bk1}.
// T2 swizzle (bank-exact): LDS[r][c] = G[r][c ^ ((r>>1)&3)] -- 16 lanes spread over all 8
// bank-groups twice (2-way = free). Applied on staging SOURCE (linear LDS dest, rule #21)
// and on the ds_read byte offset.
#define SBAR() do{ __builtin_amdgcn_s_barrier(); __builtin_amdgcn_sched_barrier(0); }while(0)
#define VMC(n) asm volatile("s_waitcnt vmcnt(" #n ")" ::: "memory")

#define STG(slot, srcp, tks, khh) do{ \
  const ushort* _s = (srcp) + (tks)*64 + (khh)*32; \
  gload16(_s,                    lds + (slot)*8192 + wid*512); \
  gload16(_s + (size_t)128*GK,   lds + (slot)*8192 + 4096 + wid*512); \
}while(0)

#define RD_A(slot, mh) do{ \
  af[0] = *reinterpret_cast<const bf16x8*>(ldsc + (slot)*16384 + wm*8192 + ((mh)*4+0)*1024 + frA); \
  af[1] = *reinterpret_cast<const bf16x8*>(ldsc + (slot)*16384 + wm*8192 + ((mh)*4+1)*1024 + frA); \
  af[2] = *reinterpret_cast<const bf16x8*>(ldsc + (slot)*16384 + wm*8192 + ((mh)*4+2)*1024 + frA); \
  af[3] = *reinterpret_cast<const bf16x8*>(ldsc + (slot)*16384 + wm*8192 + ((mh)*4+3)*1024 + frA); \
}while(0)

#define RD_B(slot) do{ \
  bfr[0] = *reinterpret_cast<const bf16x8*>(ldsc + (slot)*16384 + wn*4096 + 0*1024 + frA); \
  bfr[1] = *reinterpret_cast<const bf16x8*>(ldsc + (slot)*16384 + wn*4096 + 1*1024 + frA); \
  bfr[2] = *reinterpret_cast<const bf16x8*>(ldsc + (slot)*16384 + wn*4096 + 2*1024 + frA); \
  bfr[3] = *reinterpret_cast<const bf16x8*>(ldsc + (slot)*16384 + wn*4096 + 3*1024 + frA); \
}while(0)

#define MM(mh) do{ \
  __builtin_amdgcn_s_setprio(1); \
  _Pragma("unroll") \
  for (int mf2 = 0; mf2 < 4; mf2++) \
    _Pragma("unroll") \
    for (int nf = 0; nf < 4; nf++) \
      acc[(mh)*4+mf2][nf] = __builtin_amdgcn_mfma_f32_16x16x32_bf16(af[mf2], bfr[nf], acc[(mh)*4+mf2][nf], 0, 0, 0); \
  __builtin_amdgcn_s_setprio(0); \
}while(0)

__launch_bounds__(512, 2)
__global__ void k_gemm_qkv8(const ushort* __restrict__ A, const ushort* __restrict__ Bt,
                            const float2* __restrict__ cs,
                            ushort* __restrict__ Qh, ushort* __restrict__ Kh,
                            ushort* __restrict__ Vt){
  __shared__ short lds[65536];   // 128 KiB: 8 half-slots x 16 KB
  const int tid = threadIdx.x, lane = tid & 63, wid = tid >> 6;
  const int wm = wid >> 2, wn = wid & 3;
  const int fr = lane & 15, fq = lane >> 4;

  // XCD-bijective block swizzle (384 = 8*48)
  const int bid = blockIdx.x;
  const int b2 = (bid & 7) * 48 + (bid >> 3);
  const int by = b2 / 24, bx = b2 % 24;

  // staging source, pre-swizzled: lane row r = wid*16 + (lane>>2);
  // chunk stored at LDS pos (lane&3) comes from global chunk (lane&3) ^ ((r>>1)&3) = (lane&3)^((lane>>3)&3)
  const int rbase = wid * 16 + (lane >> 2);
  const int kup = ((lane & 3) ^ ((lane >> 3) & 3)) * 8;
  const ushort* pa = A  + (size_t)(by * 256 + rbase) * GK + kup;
  const ushort* pb = Bt + (size_t)(bx * 256 + rbase) * GK + kup;

  // ds_read per-lane byte offset: row fr, chunk fq ^ ((fr>>1)&3)  (matches staging key)
  const char* ldsc = (const char*)lds;
  const int frA = fr * 64 + ((fq * 16) ^ (((fr >> 1) & 3) << 4));

  f32x4 acc[8][4] = {};
  bf16x8 af[4], bfr[4];

  // prologue: stage K-tile 0 (4 halves) + K-tile 1 (h0) = 12 loads
  STG(0, pa, 0, 0); STG(1, pb, 0, 0); STG(2, pa, 0, 1); STG(3, pb, 0, 1);
  STG(4, pa, 1, 0); STG(5, pb, 1, 0);
  VMC(8);
  SBAR();

  #pragma unroll 1
  for (int it = 0; it < 16; ++it){
    const int tb  = 2 * it + 1;
    const int tn  = (2 * it + 2 < 32) ? 2 * it + 2 : 31;   // clamp keeps vmcnt counts uniform
    const int tn1 = (2 * it + 3 < 32) ? 2 * it + 3 : 31;
    // ph1: compute ta kh0 mh0
    RD_A(0, 0); RD_B(1); STG(6, pa, tb, 1);           SBAR(); MM(0); SBAR();
    // ph2: ta kh0 mh1
    RD_A(0, 1);          STG(7, pb, tb, 1);  VMC(6);  SBAR(); MM(1); SBAR();
    // ph3: ta kh1 mh0
    RD_A(2, 0); RD_B(3); STG(0, pa, tn, 0);           SBAR(); MM(0); SBAR();
    // ph4: ta kh1 mh1
    RD_A(2, 1);          STG(1, pb, tn, 0);  VMC(6);  SBAR(); MM(1); SBAR();
    // ph5: tb kh0 mh0
    RD_A(4, 0); RD_B(5); STG(2, pa, tn, 1);           SBAR(); MM(0); SBAR();
    // ph6: tb kh0 mh1
    RD_A(4, 1);          STG(3, pb, tn, 1);  VMC(6);  SBAR(); MM(1); SBAR();
    // ph7: tb kh1 mh0
    RD_A(6, 0); RD_B(7); STG(4, pa, tn1, 0);          SBAR(); MM(0); SBAR();
    // ph8: tb kh1 mh1
    RD_A(6, 1);          STG(5, pb, tn1, 0); VMC(6);  SBAR(); MM(1); SBAR();
  }

  // ---------------- epilogue ----------------
  const int rowb = by * 256 + wm * 128 + fq * 4;
  if (bx < 16){
    ushort* dst = (bx < 8) ? Qh : Kh;
    #pragma unroll
    for (int mf = 0; mf < 8; mf++)
      #pragma unroll
      for (int nf = 0; nf < 4; nf++){
        int col = bx * 256 + wn * 64 + nf * 16 + fr;
        int cg = col & 2047;
        int hh = cg >> 7, dd = cg & 127, jj = (cg >> 1) & 63;
        #pragma unroll
        for (int i = 0; i < 4; i++){
          int row = rowb + mf * 16 + i;
          int s = row & (S_LEN - 1), bb = row >> 11;
          float2 c2 = cs[s * 64 + jj];
          float v = acc[mf][nf][i];
          float p = __shfl_xor(v, 1);
          float o = (fr & 1) ? fmaf(p, c2.y, v * c2.x) : fmaf(v, c2.x, -p * c2.y);
          dst[((size_t)(bb * NH + hh) * S_LEN + s) * DK + dd] = f2bf(o);
        }
      }
  } else {
    #pragma unroll
    for (int mf = 0; mf < 8; mf++){
      int row0 = rowb + mf * 16;
      int s0 = row0 & (S_LEN - 1), bb = row0 >> 11;
      #pragma unroll
      for (int nf = 0; nf < 4; nf++){
        int col = (bx - 16) * 256 + wn * 64 + nf * 16 + fr;
        int hh = col >> 7, dd = col & 127;
        ushort4 o;
        o.x = f2bf(acc[mf][nf][0]); o.y = f2bf(acc[mf][nf][1]);
        o.z = f2bf(acc[mf][nf][2]); o.w = f2bf(acc[mf][nf][3]);
        *reinterpret_cast<ushort4*>(&Vt[((size_t)(bb * NH + hh) * DK + dd) * S_LEN + s0]) = o;
      }
    }
  }
}

// ---------------- GEMM: C[M][N] = A[M][K] * Bt[N][K]^T  (m97 structure, fp32 out) ----------------
__launch_bounds__(256)
__global__ void k_gemm_bt(const ushort* __restrict__ A, const ushort* __restrict__ Bt,
                          float* __restrict__ C, int M, int N, int K){
  __shared__ short lA[128 * 32];
  __shared__ short lB[128 * 32];
  const int tid = threadIdx.x;
  const int lane = tid & 63, wid = tid >> 6;
  const int wm = wid >> 1, wn = wid & 1;
  const int bx = blockIdx.x, by = blockIdx.y;
  const int fr = lane & 15, fq = lane >> 4;

  const int sr = wid * 32 + (lane >> 2);
  const int scol = (lane & 3) * 8;
  const ushort* pa = A  + (size_t)(by * 128 + sr) * K + scol;
  const ushort* pb = Bt + (size_t)(bx * 128 + sr) * K + scol;
  char* lA0 = (char*)lA + wid * 2048;
  char* lB0 = (char*)lB + wid * 2048;

  f32x4 acc[4][4] = {};
  const int arow = wm * 64, brow = wn * 64;

  for (int kk = 0; kk < K; kk += 32){
    __syncthreads();
    gload16(pa + kk,                    lA0);
    gload16(pa + (size_t)16 * K + kk,   lA0 + 1024);
    gload16(pb + kk,                    lB0);
    gload16(pb + (size_t)16 * K + kk,   lB0 + 1024);
    __syncthreads();
    bf16x8 af[4], bfr[4];
    #pragma unroll
    for (int m = 0; m < 4; m++)
      af[m] = *reinterpret_cast<const bf16x8*>(&lA[(arow + m * 16 + fr) * 32 + fq * 8]);
    #pragma unroll
    for (int n = 0; n < 4; n++)
      bfr[n] = *reinterpret_cast<const bf16x8*>(&lB[(brow + n * 16 + fr) * 32 + fq * 8]);
    #pragma unroll
    for (int m = 0; m < 4; m++)
      #pragma unroll
      for (int n = 0; n < 4; n++)
        acc[m][n] = __builtin_amdgcn_mfma_f32_16x16x32_bf16(af[m], bfr[n], acc[m][n], 0, 0, 0);
  }
  const int orow = by * 128 + wm * 64 + fq * 4;
  const int ocol = bx * 128 + wn * 64 + fr;
  #pragma unroll
  for (int m = 0; m < 4; m++)
    #pragma unroll
    for (int n = 0; n < 4; n++)
      #pragma unroll
      for (int i = 0; i < 4; i++)
        C[(size_t)(orow + m * 16 + i) * N + ocol + n * 16] = acc[m][n][i];
}

// ---------------- causal flash attention: 4-wave blocks, LDS-shared K/V, paired chunks ----------------
__launch_bounds__(256)
__global__ void k_attn(const ushort* __restrict__ Q, const ushort* __restrict__ K,
                       const ushort* __restrict__ Vt, ushort* __restrict__ O){
  __shared__ short Kt[2][64 * 128];   // [kv][d] swizzled (16KB each)
  __shared__ short Vl[2][128 * 64];   // [d][kv] swizzled (16KB each)
  __shared__ short Pl[4][16 * 64];    // per-wave P [q][kv] swizzled (2KB each)
  const int tid = threadIdx.x, lane = tid & 63, wid = tid >> 6;
  const int bid = blockIdx.x;
  const int pid = bid >> 5;           // 0..15
  const int bh = bid & 31;
  const int b = bh >> 4, h = bh & 15;
  const int fr = lane & 15, fq = lane >> 4;
  const int swz = (fr & 7) << 4;

  const ushort* kb = K  + (size_t)bh * S_LEN * DK;
  const ushort* vb = Vt + (size_t)bh * DK * S_LEN;
  char* PlB = (char*)(&Pl[wid][0]);
  const float scale = 0.08838834764831845f;   // 1/sqrt(128)
  ushort* ob = O + (size_t)b * S_LEN * DM;

  int kro[4], kco[4], vro[4], vco[4];
  #pragma unroll
  for (int jj = 0; jj < 4; jj++){
    int ins = wid * 4 + jj;
    kro[jj] = ins * 4 + (lane >> 4);
    kco[jj] = 8 * ((lane & 15) ^ (kro[jj] & 7));
    vro[jj] = ins * 8 + (lane >> 3);
    vco[jj] = 8 * ((lane & 7) ^ (vro[jj] & 7));
  }

  #pragma unroll 1
  for (int half = 0; half < 2; half++){
    const int j = half ? pid : 31 - pid;
    const int qr = j * 64 + wid * 16;
    const int nt = j + 1;

    bf16x8 qf[4];
    #pragma unroll
    for (int c = 0; c < 4; c++)
      qf[c] = *reinterpret_cast<const bf16x8*>(
          Q + ((size_t)bh * S_LEN + qr + fr) * DK + c * 32 + fq * 8);

    float mi[4], li[4];
    #pragma unroll
    for (int i = 0; i < 4; i++){ mi[i] = -1e30f; li[i] = 0.f; }
    f32x4 accO[8] = {};

    __syncthreads();
    {
      char* kd = (char*)Kt + (wid * 4) * 1024;
      char* vd = (char*)Vl + (wid * 4) * 1024;
      #pragma unroll
      for (int jj = 0; jj < 4; jj++){
        gload16(kb + (size_t)kro[jj] * DK + kco[jj],      kd + jj * 1024);
        gload16(vb + (size_t)vro[jj] * S_LEN + vco[jj],   vd + jj * 1024);
      }
    }
    __syncthreads();

    #pragma unroll 1
    for (int kt = 0; kt < nt; kt++){
      const int k0 = kt * 64;
      const int cur = kt & 1;
      if (kt + 1 < nt){
        const int k1 = k0 + 64;
        char* kd = (char*)Kt + (cur ^ 1) * 16384 + (wid * 4) * 1024;
        char* vd = (char*)Vl + (cur ^ 1) * 16384 + (wid * 4) * 1024;
        #pragma unroll
        for (int jj = 0; jj < 4; jj++){
          gload16(kb + (size_t)(k1 + kro[jj]) * DK + kco[jj],    kd + jj * 1024);
          gload16(vb + (size_t)vro[jj] * S_LEN + k1 + vco[jj],   vd + jj * 1024);
        }
      }
      const char* KtB = (const char*)Kt + cur * 16384;
      const char* VlB = (const char*)Vl + cur * 16384;

      f32x4 sc[4] = {};
      #pragma unroll
      for (int c = 0; c < 4; c++){
        bf16x8 kf[4];
        #pragma unroll
        for (int ch = 0; ch < 4; ch++)
          kf[ch] = *reinterpret_cast<const bf16x8*>(
              KtB + (ch * 16 + fr) * 256 + ((c * 64 + fq * 16) ^ swz));
        #pragma unroll
        for (int ch = 0; ch < 4; ch++)
          sc[ch] = __builtin_amdgcn_mfma_f32_16x16x32_bf16(qf[c], kf[ch], sc[ch], 0, 0, 0);
      }

      const bool needmask = (kt == nt - 1);
      #pragma unroll
      for (int ch = 0; ch < 4; ch++)
        #pragma unroll
        for (int i = 0; i < 4; i++){
          float v = sc[ch][i] * scale;
          if (needmask && (k0 + ch * 16 + fr > qr + fq * 4 + i)) v = -1e30f;
          sc[ch][i] = v;
        }
      f32x4 mx;
      #pragma unroll
      for (int i = 0; i < 4; i++)
        mx[i] = fmaxf(fmaxf(sc[0][i], sc[1][i]), fmaxf(sc[2][i], sc[3][i]));
      #pragma unroll
      for (int off = 1; off < 16; off <<= 1)
        #pragma unroll
        for (int i = 0; i < 4; i++) mx[i] = fmaxf(mx[i], __shfl_xor(mx[i], off));
      float scl[4];
      #pragma unroll
      for (int i = 0; i < 4; i++){
        float mn = fmaxf(mi[i], mx[i]);
        scl[i] = __expf(mi[i] - mn);
        mi[i] = mn;
      }
      #pragma unroll
      for (int ch = 0; ch < 4; ch++)
        #pragma unroll
        for (int i = 0; i < 4; i++) sc[ch][i] = __expf(sc[ch][i] - mi[i]);
      f32x4 rs;
      #pragma unroll
      for (int i = 0; i < 4; i++)
        rs[i] = (sc[0][i] + sc[1][i]) + (sc[2][i] + sc[3][i]);
      #pragma unroll
      for (int off = 1; off < 16; off <<= 1)
        #pragma unroll
        for (int i = 0; i < 4; i++) rs[i] += __shfl_xor(rs[i], off);
      #pragma unroll
      for (int i = 0; i < 4; i++) li[i] = li[i] * scl[i] + rs[i];
      #pragma unroll
      for (int dt = 0; dt < 8; dt++)
        #pragma unroll
        for (int i = 0; i < 4; i++) accO[dt][i] *= scl[i];

      #pragma unroll
      for (int ch = 0; ch < 4; ch++)
        #pragma unroll
        for (int i = 0; i < 4; i++){
          int q = fq * 4 + i;
          int off = q * 128 + ((ch * 32 + fr * 2) ^ ((q & 7) << 4));
          *reinterpret_cast<short*>(PlB + off) = (short)f2bf(sc[ch][i]);
        }
      bf16x8 pf[2];
      #pragma unroll
      for (int c2 = 0; c2 < 2; c2++)
        pf[c2] = *reinterpret_cast<const bf16x8*>(
            PlB + fr * 128 + ((c2 * 64 + fq * 16) ^ swz));

      #pragma unroll
      for (int dt = 0; dt < 8; dt++)
        #pragma unroll
        for (int c2 = 0; c2 < 2; c2++){
          bf16x8 vf = *reinterpret_cast<const bf16x8*>(
              VlB + (dt * 16 + fr) * 128 + ((c2 * 64 + fq * 16) ^ swz));
          accO[dt] = __builtin_amdgcn_mfma_f32_16x16x32_bf16(pf[c2], vf, accO[dt], 0, 0, 0);
        }
      __syncthreads();
    }

    float inv[4];
    #pragma unroll
    for (int i = 0; i < 4; i++) inv[i] = 1.f / li[i];
    #pragma unroll
    for (int dt = 0; dt < 8; dt++)
      #pragma unroll
      for (int i = 0; i < 4; i++){
        int row = qr + fq * 4 + i;
        ob[(size_t)row * DM + h * DK + dt * 16 + fr] = f2bf(accO[dt][i] * inv[i]);
      }
  }
}

extern "C" void kernel_launch(void* const* d_in, const int* in_sizes, int n_in,
                              void* d_out, int out_size, void* d_ws, size_t ws_size,
                              hipStream_t stream){
  const float* x  = (const float*)d_in[0];
  const float* wq = (const float*)d_in[1];
  const float* wk = (const float*)d_in[2];
  const float* wv = (const float*)d_in[3];
  const float* wo = (const float*)d_in[4];
  const int* pos  = (const int*)d_in[5];
  float* out = (float*)d_out;

  char* ws = (char*)d_ws;
  ushort* xb   = (ushort*)(ws);               // 16 MiB; Ob aliases after GEMM consumes xb
  ushort* Ob   = xb;
  ushort* wqkv = (ushort*)(ws + 16777216);    // 24 MiB; wo bf16 aliases after QKV GEMM
  ushort* wb   = wqkv;
  ushort* Qh   = (ushort*)(ws + 41943040);    // 16 MiB
  ushort* Kh   = (ushort*)(ws + 58720256);    // 16 MiB
  ushort* Vt   = (ushort*)(ws + 75497472);    // 16 MiB
  float2* cs   = (float2*)(ws + 92274688);    // 1 MiB

  const int M = BB * S_LEN;                    // 4096

  k_rope_table<<<(S_LEN * 64) / 256, 256, 0, stream>>>(pos, cs);
  k_f32_to_bf16<<<(M * DM / 4) / 256, 256, 0, stream>>>(x, xb, M * DM / 4);
  const int nw4 = DM * DM / 4;
  k_f32_to_bf16<<<nw4 / 256, 256, 0, stream>>>(wq, wqkv, nw4);
  k_f32_to_bf16<<<nw4 / 256, 256, 0, stream>>>(wk, wqkv + DM * DM, nw4);
  k_f32_to_bf16<<<nw4 / 256, 256, 0, stream>>>(wv, wqkv + 2 * DM * DM, nw4);

  k_gemm_qkv8<<<384, 512, 0, stream>>>(xb, wqkv, cs, Qh, Kh, Vt);

  k_attn<<<512, 256, 0, stream>>>(Qh, Kh, Vt, Ob);

  k_f32_to_bf16<<<nw4 / 256, 256, 0, stream>>>(wo, wb, nw4);
  k_gemm_bt<<<dim3(DM / 128, M / 128), 256, 0, stream>>>(Ob, wb, out, M, DM, DM);
}

// Round 8
// 298.326 us; speedup vs baseline: 1.5551x; 1.0542x over previous
//
#include <hip/hip_runtime.h>

#define S_LEN 2048
#define DM 2048
#define NH 16
#define DK 128
#define BB 2
#define BH (BB*NH)
#define GK 2048

typedef float f32x4 __attribute__((ext_vector_type(4)));
typedef __bf16 bf16x8 __attribute__((ext_vector_type(8)));
typedef unsigned int u32;

#define AS1 __attribute__((address_space(1)))
#define AS3 __attribute__((address_space(3)))

__device__ inline void gload16(const void* g, void* l){
  __builtin_amdgcn_global_load_lds((AS1 const u32*)g, (AS3 u32*)l, 16, 0, 0);
}

__device__ inline ushort f2bf(float f){
  unsigned u = __float_as_uint(f);
  u = (u + 0x7FFFu + ((u >> 16) & 1u)) >> 16;
  return (ushort)u;
}

// ---------------- fp32 -> bf16 (vectorized) ----------------
__global__ void k_f32_to_bf16(const float* __restrict__ in, ushort* __restrict__ out, int n4){
  int i = blockIdx.x * blockDim.x + threadIdx.x;
  if (i >= n4) return;
  float4 v = reinterpret_cast<const float4*>(in)[i];
  ushort4 o;
  o.x = f2bf(v.x); o.y = f2bf(v.y); o.z = f2bf(v.z); o.w = f2bf(v.w);
  reinterpret_cast<ushort4*>(out)[i] = o;
}

// ---------------- all 4 weights fp32->bf16 in one launch ----------------
__global__ void k_w4(const float* __restrict__ wq, const float* __restrict__ wk,
                     const float* __restrict__ wv, const float* __restrict__ wo4,
                     ushort* __restrict__ dqkv, ushort* __restrict__ dwo){
  int i = blockIdx.x * 256 + threadIdx.x;         // over 4 * (DM*DM/4), DM*DM/4 = 1<<20
  int sel = i >> 20;
  int off = i & ((1 << 20) - 1);
  const float* s = (sel == 0) ? wq : (sel == 1) ? wk : (sel == 2) ? wv : wo4;
  ushort* d = (sel < 3) ? (dqkv + (size_t)sel * DM * DM) : dwo;
  float4 v = reinterpret_cast<const float4*>(s)[off];
  ushort4 o;
  o.x = f2bf(v.x); o.y = f2bf(v.y); o.z = f2bf(v.z); o.w = f2bf(v.w);
  reinterpret_cast<ushort4*>(d)[off] = o;
}

// ---------------- rope cos/sin table [S][64] as float2 {cos,sin} ----------------
__global__ void k_rope_table(const int* __restrict__ pos, float2* __restrict__ cs){
  int idx = blockIdx.x * 256 + threadIdx.x;
  if (idx >= S_LEN * 64) return;
  int s = idx >> 6, i = idx & 63;
  float inv = expf(-0.14391156831212787f * (float)i);   // 10000^(-i/64)
  float f = (float)pos[s] * inv;
  cs[idx] = make_float2(cosf(f), sinf(f));
}

#define SBAR() do{ __builtin_amdgcn_s_barrier(); __builtin_amdgcn_sched_barrier(0); }while(0)
#define VMC(n) asm volatile("s_waitcnt vmcnt(" #n ")" ::: "memory")

// ================= fused QKV GEMM: 256x256 tile, BK=64, 8 waves, 8-phase =================
#define STG(slot, srcp, tks, khh) do{ \
  const ushort* _s = (srcp) + (tks)*64 + (khh)*32; \
  gload16(_s,                    lds + (slot)*8192 + wid*512); \
  gload16(_s + (size_t)128*GK,   lds + (slot)*8192 + 4096 + wid*512); \
}while(0)

#define RD_A(slot, mh) do{ \
  af[0] = *reinterpret_cast<const bf16x8*>(ldsc + (slot)*16384 + wm*8192 + ((mh)*4+0)*1024 + frA); \
  af[1] = *reinterpret_cast<const bf16x8*>(ldsc + (slot)*16384 + wm*8192 + ((mh)*4+1)*1024 + frA); \
  af[2] = *reinterpret_cast<const bf16x8*>(ldsc + (slot)*16384 + wm*8192 + ((mh)*4+2)*1024 + frA); \
  af[3] = *reinterpret_cast<const bf16x8*>(ldsc + (slot)*16384 + wm*8192 + ((mh)*4+3)*1024 + frA); \
}while(0)

#define RD_B(slot) do{ \
  bfr[0] = *reinterpret_cast<const bf16x8*>(ldsc + (slot)*16384 + wn*4096 + 0*1024 + frA); \
  bfr[1] = *reinterpret_cast<const bf16x8*>(ldsc + (slot)*16384 + wn*4096 + 1*1024 + frA); \
  bfr[2] = *reinterpret_cast<const bf16x8*>(ldsc + (slot)*16384 + wn*4096 + 2*1024 + frA); \
  bfr[3] = *reinterpret_cast<const bf16x8*>(ldsc + (slot)*16384 + wn*4096 + 3*1024 + frA); \
}while(0)

#define MM(mh) do{ \
  __builtin_amdgcn_s_setprio(1); \
  _Pragma("unroll") \
  for (int mf2 = 0; mf2 < 4; mf2++) \
    _Pragma("unroll") \
    for (int nf = 0; nf < 4; nf++) \
      acc[(mh)*4+mf2][nf] = __builtin_amdgcn_mfma_f32_16x16x32_bf16(af[mf2], bfr[nf], acc[(mh)*4+mf2][nf], 0, 0, 0); \
  __builtin_amdgcn_s_setprio(0); \
}while(0)

__launch_bounds__(512, 2)
__global__ void k_gemm_qkv8(const ushort* __restrict__ A, const ushort* __restrict__ Bt,
                            const float2* __restrict__ cs,
                            ushort* __restrict__ Qh, ushort* __restrict__ Kh,
                            ushort* __restrict__ Vt){
  __shared__ short lds[65536];   // 128 KiB: 8 half-slots x 16 KB
  const int tid = threadIdx.x, lane = tid & 63, wid = tid >> 6;
  const int wm = wid >> 2, wn = wid & 3;
  const int fr = lane & 15, fq = lane >> 4;

  const int bid = blockIdx.x;
  const int b2 = (bid & 7) * 48 + (bid >> 3);
  const int by = b2 / 24, bx = b2 % 24;

  const int rbase = wid * 16 + (lane >> 2);
  const int kup = ((lane & 3) ^ ((lane >> 3) & 3)) * 8;
  const ushort* pa = A  + (size_t)(by * 256 + rbase) * GK + kup;
  const ushort* pb = Bt + (size_t)(bx * 256 + rbase) * GK + kup;

  const char* ldsc = (const char*)lds;
  const int frA = fr * 64 + ((fq * 16) ^ (((fr >> 1) & 3) << 4));

  f32x4 acc[8][4] = {};
  bf16x8 af[4], bfr[4];

  STG(0, pa, 0, 0); STG(1, pb, 0, 0); STG(2, pa, 0, 1); STG(3, pb, 0, 1);
  STG(4, pa, 1, 0); STG(5, pb, 1, 0);
  VMC(8);
  SBAR();

  #pragma unroll 1
  for (int it = 0; it < 16; ++it){
    const int tb  = 2 * it + 1;
    const int tn  = (2 * it + 2 < 32) ? 2 * it + 2 : 31;
    const int tn1 = (2 * it + 3 < 32) ? 2 * it + 3 : 31;
    RD_A(0, 0); RD_B(1); STG(6, pa, tb, 1);           SBAR(); MM(0); SBAR();
    RD_A(0, 1);          STG(7, pb, tb, 1);  VMC(6);  SBAR(); MM(1); SBAR();
    RD_A(2, 0); RD_B(3); STG(0, pa, tn, 0);           SBAR(); MM(0); SBAR();
    RD_A(2, 1);          STG(1, pb, tn, 0);  VMC(6);  SBAR(); MM(1); SBAR();
    RD_A(4, 0); RD_B(5); STG(2, pa, tn, 1);           SBAR(); MM(0); SBAR();
    RD_A(4, 1);          STG(3, pb, tn, 1);  VMC(6);  SBAR(); MM(1); SBAR();
    RD_A(6, 0); RD_B(7); STG(4, pa, tn1, 0);          SBAR(); MM(0); SBAR();
    RD_A(6, 1);          STG(5, pb, tn1, 0); VMC(6);  SBAR(); MM(1); SBAR();
  }

  const int rowb = by * 256 + wm * 128 + fq * 4;
  if (bx < 16){
    ushort* dst = (bx < 8) ? Qh : Kh;
    #pragma unroll
    for (int mf = 0; mf < 8; mf++)
      #pragma unroll
      for (int nf = 0; nf < 4; nf++){
        int col = bx * 256 + wn * 64 + nf * 16 + fr;
        int cg = col & 2047;
        int hh = cg >> 7, dd = cg & 127, jj = (cg >> 1) & 63;
        #pragma unroll
        for (int i = 0; i < 4; i++){
          int row = rowb + mf * 16 + i;
          int s = row & (S_LEN - 1), bb = row >> 11;
          float2 c2 = cs[s * 64 + jj];
          float v = acc[mf][nf][i];
          float p = __shfl_xor(v, 1);
          float o = (fr & 1) ? fmaf(p, c2.y, v * c2.x) : fmaf(v, c2.x, -p * c2.y);
          dst[((size_t)(bb * NH + hh) * S_LEN + s) * DK + dd] = f2bf(o);
        }
      }
  } else {
    #pragma unroll
    for (int mf = 0; mf < 8; mf++){
      int row0 = rowb + mf * 16;
      int s0 = row0 & (S_LEN - 1), bb = row0 >> 11;
      #pragma unroll
      for (int nf = 0; nf < 4; nf++){
        int col = (bx - 16) * 256 + wn * 64 + nf * 16 + fr;
        int hh = col >> 7, dd = col & 127;
        ushort4 o;
        o.x = f2bf(acc[mf][nf][0]); o.y = f2bf(acc[mf][nf][1]);
        o.z = f2bf(acc[mf][nf][2]); o.w = f2bf(acc[mf][nf][3]);
        *reinterpret_cast<ushort4*>(&Vt[((size_t)(bb * NH + hh) * DK + dd) * S_LEN + s0]) = o;
      }
    }
  }
}

// ================= WO GEMM: 256x128 tile, BK=64, 8 waves, 8-phase, fp32 out =================
// Ring: 4 A-slots [256][32] (16KB) at i*16384B + 4 B-slots [128][32] (8KB) at 65536+i*8192B = 96KB.
// Wave grid 4m x 2n, wave tile 64x64, acc[4][4]. Grid 16x16 = 256 tiles = 1/CU exact.
#define WSTG_A(si, tks, khh) do{ \
  const ushort* _s = pa + (tks)*64 + (khh)*32; \
  gload16(_s,                  lds + (si)*8192 + wid*512); \
  gload16(_s + (size_t)128*GK, lds + (si)*8192 + 4096 + wid*512); \
}while(0)
#define WSTG_B(si, tks, khh) do{ \
  const ushort* _s = pb + (tks)*64 + (khh)*32; \
  gload16(_s, lds + 32768 + (si)*4096 + wid*512); \
}while(0)
#define WRD_A(si, mhf) do{ \
  af[0] = *reinterpret_cast<const bf16x8*>(ldsc + (si)*16384 + wm*4096 + ((mhf)*2+0)*1024 + frA); \
  af[1] = *reinterpret_cast<const bf16x8*>(ldsc + (si)*16384 + wm*4096 + ((mhf)*2+1)*1024 + frA); \
}while(0)
#define WRD_B(si) do{ \
  bfr[0] = *reinterpret_cast<const bf16x8*>(ldsc + 65536 + (si)*8192 + wn*4096 + 0*1024 + frA); \
  bfr[1] = *reinterpret_cast<const bf16x8*>(ldsc + 65536 + (si)*8192 + wn*4096 + 1*1024 + frA); \
  bfr[2] = *reinterpret_cast<const bf16x8*>(ldsc + 65536 + (si)*8192 + wn*4096 + 2*1024 + frA); \
  bfr[3] = *reinterpret_cast<const bf16x8*>(ldsc + 65536 + (si)*8192 + wn*4096 + 3*1024 + frA); \
}while(0)
#define WMM(mhf) do{ \
  __builtin_amdgcn_s_setprio(1); \
  _Pragma("unroll") \
  for (int k2 = 0; k2 < 2; k2++) \
    _Pragma("unroll") \
    for (int nf = 0; nf < 4; nf++) \
      acc[(mhf)*2+k2][nf] = __builtin_amdgcn_mfma_f32_16x16x32_bf16(af[k2], bfr[nf], acc[(mhf)*2+k2][nf], 0, 0, 0); \
  __builtin_amdgcn_s_setprio(0); \
}while(0)

__launch_bounds__(512, 2)
__global__ void k_gemm_wo(const ushort* __restrict__ A, const ushort* __restrict__ Bt,
                          float* __restrict__ C){
  __shared__ short lds[49152];   // 96 KiB
  const int tid = threadIdx.x, lane = tid & 63, wid = tid >> 6;
  const int wm = wid >> 1, wn = wid & 1;
  const int fr = lane & 15, fq = lane >> 4;

  const int bid = blockIdx.x;                  // 256 = 8 * 32, bijective XCD swizzle
  const int b2 = (bid & 7) * 32 + (bid >> 3);
  const int by = b2 >> 4, bx = b2 & 15;

  const int rbase = wid * 16 + (lane >> 2);
  const int kup = ((lane & 3) ^ ((lane >> 3) & 3)) * 8;
  const ushort* pa = A  + (size_t)(by * 256 + rbase) * GK + kup;
  const ushort* pb = Bt + (size_t)(bx * 128 + rbase) * GK + kup;

  const char* ldsc = (const char*)lds;
  const int frA = fr * 64 + ((fq * 16) ^ (((fr >> 1) & 3) << 4));

  f32x4 acc[4][4] = {};
  bf16x8 af[2], bfr[4];

  // prologue: A0,B0 (t0 kh0), A1,B1 (t0 kh1), A2,B2 (t1 kh0) = 9 loads
  WSTG_A(0, 0, 0); WSTG_B(0, 0, 0); WSTG_A(1, 0, 1); WSTG_B(1, 0, 1);
  WSTG_A(2, 1, 0); WSTG_B(2, 1, 0);
  VMC(6);
  SBAR();

  #pragma unroll 1
  for (int it = 0; it < 16; ++it){
    const int tb  = 2 * it + 1;
    const int tn  = (2 * it + 2 < 32) ? 2 * it + 2 : 31;
    const int tn1 = (2 * it + 3 < 32) ? 2 * it + 3 : 31;
    WRD_A(0, 0); WRD_B(0); WSTG_A(3, tb, 1);            SBAR(); WMM(0); SBAR();
    WRD_A(0, 1);           WSTG_B(3, tb, 1);  VMC(6);   SBAR(); WMM(1); SBAR();
    WRD_A(1, 0); WRD_B(1); WSTG_A(0, tn, 0);            SBAR(); WMM(0); SBAR();
    WRD_A(1, 1);           WSTG_B(0, tn, 0);  VMC(6);   SBAR(); WMM(1); SBAR();
    WRD_A(2, 0); WRD_B(2); WSTG_A(1, tn, 1);            SBAR(); WMM(0); SBAR();
    WRD_A(2, 1);           WSTG_B(1, tn, 1);  VMC(6);   SBAR(); WMM(1); SBAR();
    WRD_A(3, 0); WRD_B(3); WSTG_A(2, tn1, 0);           SBAR(); WMM(0); SBAR();
    WRD_A(3, 1);           WSTG_B(2, tn1, 0); VMC(6);   SBAR(); WMM(1); SBAR();
  }

  const int orow = by * 256 + wm * 64 + fq * 4;
  const int ocol = bx * 128 + wn * 64 + fr;
  #pragma unroll
  for (int mf = 0; mf < 4; mf++)
    #pragma unroll
    for (int nf = 0; nf < 4; nf++)
      #pragma unroll
      for (int i = 0; i < 4; i++)
        C[(size_t)(orow + mf * 16 + i) * DM + ocol + nf * 16] = acc[mf][nf][i];
}

// ---------------- causal flash attention: 8-wave blocks, 128-row chunks, paired ----------------
// 256 blocks x 512 thr (1/CU). Block (pid,bh): chunk jA=15-pid then jB=pid (128 q-rows each).
// Work = (2jA+2)+(2jB+2) = 34 kv-tiles, uniform. Wave w owns rows [128j+16w, +16).
// K[64][128]+V[128][64] double-buffered LDS via swizzled global_load_lds, shared by 8 waves.
__launch_bounds__(512)
__global__ void k_attn(const ushort* __restrict__ Q, const ushort* __restrict__ K,
                       const ushort* __restrict__ Vt, ushort* __restrict__ O){
  __shared__ short Kt[2][64 * 128];   // [kv][d] swizzled (16KB each)
  __shared__ short Vl[2][128 * 64];   // [d][kv] swizzled (16KB each)
  __shared__ short Pl[8][16 * 64];    // per-wave P [q][kv] swizzled (2KB each)
  const int tid = threadIdx.x, lane = tid & 63, wid = tid >> 6;
  const int bid = blockIdx.x;
  const int pid = bid >> 5;           // 0..7
  const int bh = bid & 31;
  const int b = bh >> 4, h = bh & 15;
  const int fr = lane & 15, fq = lane >> 4;
  const int swz = (fr & 7) << 4;

  const ushort* kb = K  + (size_t)bh * S_LEN * DK;
  const ushort* vb = Vt + (size_t)bh * DK * S_LEN;
  char* PlB = (char*)Pl + wid * 2048;
  const float scale = 0.08838834764831845f;   // 1/sqrt(128)
  ushort* ob = O + (size_t)b * S_LEN * DM;

  // per-wave staging: 2 instrs each for K and V; instr ins = wid*2 + jj
  int kro[2], kco[2], vro[2], vco[2];
  #pragma unroll
  for (int jj = 0; jj < 2; jj++){
    int ins = wid * 2 + jj;
    kro[jj] = ins * 4 + (lane >> 4);
    kco[jj] = 8 * ((lane & 15) ^ (kro[jj] & 7));
    vro[jj] = ins * 8 + (lane >> 3);
    vco[jj] = 8 * ((lane & 7) ^ (vro[jj] & 7));
  }

  #pragma unroll 1
  for (int half = 0; half < 2; half++){
    const int j = half ? pid : 15 - pid;
    const int qr = j * 128 + wid * 16;
    const int nt = 2 * j + 2;

    bf16x8 qf[4];
    #pragma unroll
    for (int c = 0; c < 4; c++)
      qf[c] = *reinterpret_cast<const bf16x8*>(
          Q + ((size_t)bh * S_LEN + qr + fr) * DK + c * 32 + fq * 8);

    float mi[4], li[4];
    #pragma unroll
    for (int i = 0; i < 4; i++){ mi[i] = -1e30f; li[i] = 0.f; }
    f32x4 accO[8] = {};

    __syncthreads();    // protect buffers from previous chunk's readers
    #pragma unroll
    for (int jj = 0; jj < 2; jj++){
      int ins = wid * 2 + jj;
      gload16(kb + (size_t)kro[jj] * DK + kco[jj],      (char*)Kt + ins * 1024);
      gload16(vb + (size_t)vro[jj] * S_LEN + vco[jj],   (char*)Vl + ins * 1024);
    }
    __syncthreads();

    #pragma unroll 1
    for (int kt = 0; kt < nt; kt++){
      const int k0 = kt * 64;
      const int cur = kt & 1;
      if (kt + 1 < nt){
        const int k1 = k0 + 64;
        #pragma unroll
        for (int jj = 0; jj < 2; jj++){
          int ins = wid * 2 + jj;
          gload16(kb + (size_t)(k1 + kro[jj]) * DK + kco[jj],  (char*)Kt + (cur ^ 1) * 16384 + ins * 1024);
          gload16(vb + (size_t)vro[jj] * S_LEN + k1 + vco[jj], (char*)Vl + (cur ^ 1) * 16384 + ins * 1024);
        }
      }
      const char* KtB = (const char*)Kt + cur * 16384;
      const char* VlB = (const char*)Vl + cur * 16384;

      f32x4 sc[4] = {};
      #pragma unroll
      for (int c = 0; c < 4; c++){
        bf16x8 kf[4];
        #pragma unroll
        for (int ch = 0; ch < 4; ch++)
          kf[ch] = *reinterpret_cast<const bf16x8*>(
              KtB + (ch * 16 + fr) * 256 + ((c * 64 + fq * 16) ^ swz));
        #pragma unroll
        for (int ch = 0; ch < 4; ch++)
          sc[ch] = __builtin_amdgcn_mfma_f32_16x16x32_bf16(qf[c], kf[ch], sc[ch], 0, 0, 0);
      }

      const bool needmask = (k0 + 63 > qr);
      #pragma unroll
      for (int ch = 0; ch < 4; ch++)
        #pragma unroll
        for (int i = 0; i < 4; i++){
          float v = sc[ch][i] * scale;
          if (needmask && (k0 + ch * 16 + fr > qr + fq * 4 + i)) v = -1e30f;
          sc[ch][i] = v;
        }
      f32x4 mx;
      #pragma unroll
      for (int i = 0; i < 4; i++)
        mx[i] = fmaxf(fmaxf(sc[0][i], sc[1][i]), fmaxf(sc[2][i], sc[3][i]));
      #pragma unroll
      for (int off = 1; off < 16; off <<= 1)
        #pragma unroll
        for (int i = 0; i < 4; i++) mx[i] = fmaxf(mx[i], __shfl_xor(mx[i], off));
      float scl[4];
      #pragma unroll
      for (int i = 0; i < 4; i++){
        float mn = fmaxf(mi[i], mx[i]);
        scl[i] = __expf(mi[i] - mn);
        mi[i] = mn;
      }
      #pragma unroll
      for (int ch = 0; ch < 4; ch++)
        #pragma unroll
        for (int i = 0; i < 4; i++) sc[ch][i] = __expf(sc[ch][i] - mi[i]);
      f32x4 rs;
      #pragma unroll
      for (int i = 0; i < 4; i++)
        rs[i] = (sc[0][i] + sc[1][i]) + (sc[2][i] + sc[3][i]);
      #pragma unroll
      for (int off = 1; off < 16; off <<= 1)
        #pragma unroll
        for (int i = 0; i < 4; i++) rs[i] += __shfl_xor(rs[i], off);
      #pragma unroll
      for (int i = 0; i < 4; i++) li[i] = li[i] * scl[i] + rs[i];
      #pragma unroll
      for (int dt = 0; dt < 8; dt++)
        #pragma unroll
        for (int i = 0; i < 4; i++) accO[dt][i] *= scl[i];

      // P -> per-wave LDS (bf16, swizzled), same-wave in-order, no barrier
      #pragma unroll
      for (int ch = 0; ch < 4; ch++)
        #pragma unroll
        for (int i = 0; i < 4; i++){
          int q = fq * 4 + i;
          int off = q * 128 + ((ch * 32 + fr * 2) ^ ((q & 7) << 4));
          *reinterpret_cast<short*>(PlB + off) = (short)f2bf(sc[ch][i]);
        }
      bf16x8 pf[2];
      #pragma unroll
      for (int c2 = 0; c2 < 2; c2++)
        pf[c2] = *reinterpret_cast<const bf16x8*>(
            PlB + fr * 128 + ((c2 * 64 + fq * 16) ^ swz));

      #pragma unroll
      for (int dt = 0; dt < 8; dt++)
        #pragma unroll
        for (int c2 = 0; c2 < 2; c2++){
          bf16x8 vf = *reinterpret_cast<const bf16x8*>(
              VlB + (dt * 16 + fr) * 128 + ((c2 * 64 + fq * 16) ^ swz));
          accO[dt] = __builtin_amdgcn_mfma_f32_16x16x32_bf16(pf[c2], vf, accO[dt], 0, 0, 0);
        }
      __syncthreads();
    }

    float inv[4];
    #pragma unroll
    for (int i = 0; i < 4; i++) inv[i] = 1.f / li[i];
    #pragma unroll
    for (int dt = 0; dt < 8; dt++)
      #pragma unroll
      for (int i = 0; i < 4; i++){
        int row = qr + fq * 4 + i;
        ob[(size_t)row * DM + h * DK + dt * 16 + fr] = f2bf(accO[dt][i] * inv[i]);
      }
  }
}

extern "C" void kernel_launch(void* const* d_in, const int* in_sizes, int n_in,
                              void* d_out, int out_size, void* d_ws, size_t ws_size,
                              hipStream_t stream){
  const float* x  = (const float*)d_in[0];
  const float* wq = (const float*)d_in[1];
  const float* wk = (const float*)d_in[2];
  const float* wv = (const float*)d_in[3];
  const float* wo = (const float*)d_in[4];
  const int* pos  = (const int*)d_in[5];
  float* out = (float*)d_out;

  char* ws = (char*)d_ws;
  ushort* xb   = (ushort*)(ws);               // 16 MiB; Ob aliases after QKV GEMM consumes xb
  ushort* Ob   = xb;
  ushort* wqkv = (ushort*)(ws + 16777216);    // 24 MiB
  ushort* Qh   = (ushort*)(ws + 41943040);    // 16 MiB
  ushort* Kh   = (ushort*)(ws + 58720256);    // 16 MiB
  ushort* Vt   = (ushort*)(ws + 75497472);    // 16 MiB
  float2* cs   = (float2*)(ws + 92274688);    // 1 MiB
  ushort* wob  = (ushort*)(ws + 93323264);    // 8 MiB

  const int M = BB * S_LEN;                    // 4096

  k_rope_table<<<(S_LEN * 64) / 256, 256, 0, stream>>>(pos, cs);
  k_f32_to_bf16<<<(M * DM / 4) / 256, 256, 0, stream>>>(x, xb, M * DM / 4);
  k_w4<<<4 * (DM * DM / 4) / 256, 256, 0, stream>>>(wq, wk, wv, wo, wqkv, wob);

  k_gemm_qkv8<<<384, 512, 0, stream>>>(xb, wqkv, cs, Qh, Kh, Vt);

  k_attn<<<256, 512, 0, stream>>>(Qh, Kh, Vt, Ob);

  k_gemm_wo<<<256, 512, 0, stream>>>(Ob, wob, out);
}

// Round 9
// 282.337 us; speedup vs baseline: 1.6432x; 1.0566x over previous
//
#include <hip/hip_runtime.h>

#define S_LEN 2048
#define DM 2048
#define NH 16
#define DK 128
#define BB 2
#define BH (BB*NH)
#define GK 2048

typedef float f32x4 __attribute__((ext_vector_type(4)));
typedef __bf16 bf16x8 __attribute__((ext_vector_type(8)));
typedef unsigned int u32;

#define AS1 __attribute__((address_space(1)))
#define AS3 __attribute__((address_space(3)))

__device__ inline void gload16(const void* g, void* l){
  __builtin_amdgcn_global_load_lds((AS1 const u32*)g, (AS3 u32*)l, 16, 0, 0);
}

__device__ inline ushort f2bf(float f){
  unsigned u = __float_as_uint(f);
  u = (u + 0x7FFFu + ((u >> 16) & 1u)) >> 16;
  return (ushort)u;
}

// ---------------- fp32 -> bf16 (vectorized) ----------------
__global__ void k_f32_to_bf16(const float* __restrict__ in, ushort* __restrict__ out, int n4){
  int i = blockIdx.x * blockDim.x + threadIdx.x;
  if (i >= n4) return;
  float4 v = reinterpret_cast<const float4*>(in)[i];
  ushort4 o;
  o.x = f2bf(v.x); o.y = f2bf(v.y); o.z = f2bf(v.z); o.w = f2bf(v.w);
  reinterpret_cast<ushort4*>(out)[i] = o;
}

// ---------------- all 4 weights fp32->bf16 in one launch ----------------
__global__ void k_w4(const float* __restrict__ wq, const float* __restrict__ wk,
                     const float* __restrict__ wv, const float* __restrict__ wo4,
                     ushort* __restrict__ dqkv, ushort* __restrict__ dwo){
  int i = blockIdx.x * 256 + threadIdx.x;
  int sel = i >> 20;
  int off = i & ((1 << 20) - 1);
  const float* s = (sel == 0) ? wq : (sel == 1) ? wk : (sel == 2) ? wv : wo4;
  ushort* d = (sel < 3) ? (dqkv + (size_t)sel * DM * DM) : dwo;
  float4 v = reinterpret_cast<const float4*>(s)[off];
  ushort4 o;
  o.x = f2bf(v.x); o.y = f2bf(v.y); o.z = f2bf(v.z); o.w = f2bf(v.w);
  reinterpret_cast<ushort4*>(d)[off] = o;
}

// ---------------- rope cos/sin table [S][64] as float2 {cos,sin} ----------------
__global__ void k_rope_table(const int* __restrict__ pos, float2* __restrict__ cs){
  int idx = blockIdx.x * 256 + threadIdx.x;
  if (idx >= S_LEN * 64) return;
  int s = idx >> 6, i = idx & 63;
  float inv = expf(-0.14391156831212787f * (float)i);   // 10000^(-i/64)
  float f = (float)pos[s] * inv;
  cs[idx] = make_float2(cosf(f), sinf(f));
}

#define SBAR() do{ __builtin_amdgcn_s_barrier(); __builtin_amdgcn_sched_barrier(0); }while(0)
#define VMC(n) asm volatile("s_waitcnt vmcnt(" #n ")" ::: "memory")

// ================= Q+K GEMM: 256x256 tile, BK=64, 8 waves, 8-phase =================
// Grid 16x16 = 256 tiles = exactly 1/CU (no tail). N=4096 (Q|K). RoPE epilogue.
#define STG(slot, srcp, tks, khh) do{ \
  const ushort* _s = (srcp) + (tks)*64 + (khh)*32; \
  gload16(_s,                    lds + (slot)*8192 + wid*512); \
  gload16(_s + (size_t)128*GK,   lds + (slot)*8192 + 4096 + wid*512); \
}while(0)

#define RD_A(slot, mh) do{ \
  af[0] = *reinterpret_cast<const bf16x8*>(ldsc + (slot)*16384 + wm*8192 + ((mh)*4+0)*1024 + frA); \
  af[1] = *reinterpret_cast<const bf16x8*>(ldsc + (slot)*16384 + wm*8192 + ((mh)*4+1)*1024 + frA); \
  af[2] = *reinterpret_cast<const bf16x8*>(ldsc + (slot)*16384 + wm*8192 + ((mh)*4+2)*1024 + frA); \
  af[3] = *reinterpret_cast<const bf16x8*>(ldsc + (slot)*16384 + wm*8192 + ((mh)*4+3)*1024 + frA); \
}while(0)

#define RD_B(slot) do{ \
  bfr[0] = *reinterpret_cast<const bf16x8*>(ldsc + (slot)*16384 + wn*4096 + 0*1024 + frA); \
  bfr[1] = *reinterpret_cast<const bf16x8*>(ldsc + (slot)*16384 + wn*4096 + 1*1024 + frA); \
  bfr[2] = *reinterpret_cast<const bf16x8*>(ldsc + (slot)*16384 + wn*4096 + 2*1024 + frA); \
  bfr[3] = *reinterpret_cast<const bf16x8*>(ldsc + (slot)*16384 + wn*4096 + 3*1024 + frA); \
}while(0)

#define MM(mh) do{ \
  __builtin_amdgcn_s_setprio(1); \
  _Pragma("unroll") \
  for (int mf2 = 0; mf2 < 4; mf2++) \
    _Pragma("unroll") \
    for (int nf = 0; nf < 4; nf++) \
      acc[(mh)*4+mf2][nf] = __builtin_amdgcn_mfma_f32_16x16x32_bf16(af[mf2], bfr[nf], acc[(mh)*4+mf2][nf], 0, 0, 0); \
  __builtin_amdgcn_s_setprio(0); \
}while(0)

__launch_bounds__(512, 2)
__global__ void k_gemm_qk(const ushort* __restrict__ A, const ushort* __restrict__ Bt,
                          const float2* __restrict__ cs,
                          ushort* __restrict__ Qh, ushort* __restrict__ Kh){
  __shared__ short lds[65536];   // 128 KiB: 8 half-slots x 16 KB
  const int tid = threadIdx.x, lane = tid & 63, wid = tid >> 6;
  const int wm = wid >> 2, wn = wid & 3;
  const int fr = lane & 15, fq = lane >> 4;

  const int bid = blockIdx.x;                  // 256 = 8*32, bijective XCD swizzle
  const int b2 = (bid & 7) * 32 + (bid >> 3);
  const int by = b2 >> 4, bx = b2 & 15;

  const int rbase = wid * 16 + (lane >> 2);
  const int kup = ((lane & 3) ^ ((lane >> 3) & 3)) * 8;
  const ushort* pa = A  + (size_t)(by * 256 + rbase) * GK + kup;
  const ushort* pb = Bt + (size_t)(bx * 256 + rbase) * GK + kup;

  const char* ldsc = (const char*)lds;
  const int frA = fr * 64 + ((fq * 16) ^ (((fr >> 1) & 3) << 4));

  f32x4 acc[8][4] = {};
  bf16x8 af[4], bfr[4];

  STG(0, pa, 0, 0); STG(1, pb, 0, 0); STG(2, pa, 0, 1); STG(3, pb, 0, 1);
  STG(4, pa, 1, 0); STG(5, pb, 1, 0);
  VMC(8);
  SBAR();

  #pragma unroll 1
  for (int it = 0; it < 16; ++it){
    const int tb  = 2 * it + 1;
    const int tn  = (2 * it + 2 < 32) ? 2 * it + 2 : 31;
    const int tn1 = (2 * it + 3 < 32) ? 2 * it + 3 : 31;
    RD_A(0, 0); RD_B(1); STG(6, pa, tb, 1);           SBAR(); MM(0); SBAR();
    RD_A(0, 1);          STG(7, pb, tb, 1);  VMC(6);  SBAR(); MM(1); SBAR();
    RD_A(2, 0); RD_B(3); STG(0, pa, tn, 0);           SBAR(); MM(0); SBAR();
    RD_A(2, 1);          STG(1, pb, tn, 0);  VMC(6);  SBAR(); MM(1); SBAR();
    RD_A(4, 0); RD_B(5); STG(2, pa, tn, 1);           SBAR(); MM(0); SBAR();
    RD_A(4, 1);          STG(3, pb, tn, 1);  VMC(6);  SBAR(); MM(1); SBAR();
    RD_A(6, 0); RD_B(7); STG(4, pa, tn1, 0);          SBAR(); MM(0); SBAR();
    RD_A(6, 1);          STG(5, pb, tn1, 0); VMC(6);  SBAR(); MM(1); SBAR();
  }

  // epilogue: RoPE (shfl pair) -> bf16 [bh][s][d]
  const int rowb = by * 256 + wm * 128 + fq * 4;
  ushort* dst = (bx < 8) ? Qh : Kh;
  #pragma unroll
  for (int mf = 0; mf < 8; mf++)
    #pragma unroll
    for (int nf = 0; nf < 4; nf++){
      int col = bx * 256 + wn * 64 + nf * 16 + fr;
      int cg = col & 2047;
      int hh = cg >> 7, dd = cg & 127, jj = (cg >> 1) & 63;
      #pragma unroll
      for (int i = 0; i < 4; i++){
        int row = rowb + mf * 16 + i;
        int s = row & (S_LEN - 1), bb = row >> 11;
        float2 c2 = cs[s * 64 + jj];
        float v = acc[mf][nf][i];
        float p = __shfl_xor(v, 1);
        float o = (fr & 1) ? fmaf(p, c2.y, v * c2.x) : fmaf(v, c2.x, -p * c2.y);
        dst[((size_t)(bb * NH + hh) * S_LEN + s) * DK + dd] = f2bf(o);
      }
    }
}

// ================= 256x128 8-phase skeleton (shared by V GEMM and WO GEMM) =================
// Ring: 4 A-slots [256][32] (16KB) + 4 B-slots [128][32] (8KB) = 96KB. Grid 16x16 = 1/CU exact.
#define WSTG_A(si, tks, khh) do{ \
  const ushort* _s = pa + (tks)*64 + (khh)*32; \
  gload16(_s,                  lds + (si)*8192 + wid*512); \
  gload16(_s + (size_t)128*GK, lds + (si)*8192 + 4096 + wid*512); \
}while(0)
#define WSTG_B(si, tks, khh) do{ \
  const ushort* _s = pb + (tks)*64 + (khh)*32; \
  gload16(_s, lds + 32768 + (si)*4096 + wid*512); \
}while(0)
#define WRD_A(si, mhf) do{ \
  af[0] = *reinterpret_cast<const bf16x8*>(ldsc + (si)*16384 + wm*4096 + ((mhf)*2+0)*1024 + frA); \
  af[1] = *reinterpret_cast<const bf16x8*>(ldsc + (si)*16384 + wm*4096 + ((mhf)*2+1)*1024 + frA); \
}while(0)
#define WRD_B(si) do{ \
  bfr[0] = *reinterpret_cast<const bf16x8*>(ldsc + 65536 + (si)*8192 + wn*4096 + 0*1024 + frA); \
  bfr[1] = *reinterpret_cast<const bf16x8*>(ldsc + 65536 + (si)*8192 + wn*4096 + 1*1024 + frA); \
  bfr[2] = *reinterpret_cast<const bf16x8*>(ldsc + 65536 + (si)*8192 + wn*4096 + 2*1024 + frA); \
  bfr[3] = *reinterpret_cast<const bf16x8*>(ldsc + 65536 + (si)*8192 + wn*4096 + 3*1024 + frA); \
}while(0)
#define WMM(mhf) do{ \
  __builtin_amdgcn_s_setprio(1); \
  _Pragma("unroll") \
  for (int k2 = 0; k2 < 2; k2++) \
    _Pragma("unroll") \
    for (int nf = 0; nf < 4; nf++) \
      acc[(mhf)*2+k2][nf] = __builtin_amdgcn_mfma_f32_16x16x32_bf16(af[k2], bfr[nf], acc[(mhf)*2+k2][nf], 0, 0, 0); \
  __builtin_amdgcn_s_setprio(0); \
}while(0)

#define WBODY() \
  WSTG_A(0, 0, 0); WSTG_B(0, 0, 0); WSTG_A(1, 0, 1); WSTG_B(1, 0, 1); \
  WSTG_A(2, 1, 0); WSTG_B(2, 1, 0); \
  VMC(6); \
  SBAR(); \
  _Pragma("unroll 1") \
  for (int it = 0; it < 16; ++it){ \
    const int tb  = 2 * it + 1; \
    const int tn  = (2 * it + 2 < 32) ? 2 * it + 2 : 31; \
    const int tn1 = (2 * it + 3 < 32) ? 2 * it + 3 : 31; \
    WRD_A(0, 0); WRD_B(0); WSTG_A(3, tb, 1);            SBAR(); WMM(0); SBAR(); \
    WRD_A(0, 1);           WSTG_B(3, tb, 1);  VMC(6);   SBAR(); WMM(1); SBAR(); \
    WRD_A(1, 0); WRD_B(1); WSTG_A(0, tn, 0);            SBAR(); WMM(0); SBAR(); \
    WRD_A(1, 1);           WSTG_B(0, tn, 0);  VMC(6);   SBAR(); WMM(1); SBAR(); \
    WRD_A(2, 0); WRD_B(2); WSTG_A(1, tn, 1);            SBAR(); WMM(0); SBAR(); \
    WRD_A(2, 1);           WSTG_B(1, tn, 1);  VMC(6);   SBAR(); WMM(1); SBAR(); \
    WRD_A(3, 0); WRD_B(3); WSTG_A(2, tn1, 0);           SBAR(); WMM(0); SBAR(); \
    WRD_A(3, 1);           WSTG_B(2, tn1, 0); VMC(6);   SBAR(); WMM(1); SBAR(); \
  }

// ---- V GEMM: output bf16 transposed to Vt[bh][d][s] ----
__launch_bounds__(512, 2)
__global__ void k_gemm_v(const ushort* __restrict__ A, const ushort* __restrict__ Bt,
                         ushort* __restrict__ Vt){
  __shared__ short lds[49152];   // 96 KiB
  const int tid = threadIdx.x, lane = tid & 63, wid = tid >> 6;
  const int wm = wid >> 1, wn = wid & 1;
  const int fr = lane & 15, fq = lane >> 4;

  const int bid = blockIdx.x;                  // 256 = 8*32, bijective XCD swizzle
  const int b2 = (bid & 7) * 32 + (bid >> 3);
  const int by = b2 >> 4, bx = b2 & 15;

  const int rbase = wid * 16 + (lane >> 2);
  const int kup = ((lane & 3) ^ ((lane >> 3) & 3)) * 8;
  const ushort* pa = A  + (size_t)(by * 256 + rbase) * GK + kup;
  const ushort* pb = Bt + (size_t)(bx * 128 + rbase) * GK + kup;

  const char* ldsc = (const char*)lds;
  const int frA = fr * 64 + ((fq * 16) ^ (((fr >> 1) & 3) << 4));

  f32x4 acc[4][4] = {};
  bf16x8 af[2], bfr[4];

  WBODY();

  const int rowb = by * 256 + wm * 64 + fq * 4;
  #pragma unroll
  for (int mf = 0; mf < 4; mf++){
    int row0 = rowb + mf * 16;
    int s0 = row0 & (S_LEN - 1), bb = row0 >> 11;
    #pragma unroll
    for (int nf = 0; nf < 4; nf++){
      int col = bx * 128 + wn * 64 + nf * 16 + fr;
      int hh = col >> 7, dd = col & 127;
      ushort4 o;
      o.x = f2bf(acc[mf][nf][0]); o.y = f2bf(acc[mf][nf][1]);
      o.z = f2bf(acc[mf][nf][2]); o.w = f2bf(acc[mf][nf][3]);
      *reinterpret_cast<ushort4*>(&Vt[((size_t)(bb * NH + hh) * DK + dd) * S_LEN + s0]) = o;
    }
  }
}

// ---- WO GEMM: fp32 out ----
__launch_bounds__(512, 2)
__global__ void k_gemm_wo(const ushort* __restrict__ A, const ushort* __restrict__ Bt,
                          float* __restrict__ C){
  __shared__ short lds[49152];   // 96 KiB
  const int tid = threadIdx.x, lane = tid & 63, wid = tid >> 6;
  const int wm = wid >> 1, wn = wid & 1;
  const int fr = lane & 15, fq = lane >> 4;

  const int bid = blockIdx.x;
  const int b2 = (bid & 7) * 32 + (bid >> 3);
  const int by = b2 >> 4, bx = b2 & 15;

  const int rbase = wid * 16 + (lane >> 2);
  const int kup = ((lane & 3) ^ ((lane >> 3) & 3)) * 8;
  const ushort* pa = A  + (size_t)(by * 256 + rbase) * GK + kup;
  const ushort* pb = Bt + (size_t)(bx * 128 + rbase) * GK + kup;

  const char* ldsc = (const char*)lds;
  const int frA = fr * 64 + ((fq * 16) ^ (((fr >> 1) & 3) << 4));

  f32x4 acc[4][4] = {};
  bf16x8 af[2], bfr[4];

  WBODY();

  const int orow = by * 256 + wm * 64 + fq * 4;
  const int ocol = bx * 128 + wn * 64 + fr;
  #pragma unroll
  for (int mf = 0; mf < 4; mf++)
    #pragma unroll
    for (int nf = 0; nf < 4; nf++)
      #pragma unroll
      for (int i = 0; i < 4; i++)
        C[(size_t)(orow + mf * 16 + i) * DM + ocol + nf * 16] = acc[mf][nf][i];
}

// ---------------- causal flash attention: 8-wave blocks, 128-row chunks, paired ----------------
__launch_bounds__(512)
__global__ void k_attn(const ushort* __restrict__ Q, const ushort* __restrict__ K,
                       const ushort* __restrict__ Vt, ushort* __restrict__ O){
  __shared__ short Kt[2][64 * 128];   // [kv][d] swizzled (16KB each)
  __shared__ short Vl[2][128 * 64];   // [d][kv] swizzled (16KB each)
  __shared__ short Pl[8][16 * 64];    // per-wave P [q][kv] swizzled (2KB each)
  const int tid = threadIdx.x, lane = tid & 63, wid = tid >> 6;
  const int bid = blockIdx.x;
  const int pid = bid >> 5;           // 0..7
  const int bh = bid & 31;
  const int b = bh >> 4, h = bh & 15;
  const int fr = lane & 15, fq = lane >> 4;
  const int swz = (fr & 7) << 4;

  const ushort* kb = K  + (size_t)bh * S_LEN * DK;
  const ushort* vb = Vt + (size_t)bh * DK * S_LEN;
  char* PlB = (char*)Pl + wid * 2048;
  const float scale = 0.08838834764831845f;   // 1/sqrt(128)
  ushort* ob = O + (size_t)b * S_LEN * DM;

  int kro[2], kco[2], vro[2], vco[2];
  #pragma unroll
  for (int jj = 0; jj < 2; jj++){
    int ins = wid * 2 + jj;
    kro[jj] = ins * 4 + (lane >> 4);
    kco[jj] = 8 * ((lane & 15) ^ (kro[jj] & 7));
    vro[jj] = ins * 8 + (lane >> 3);
    vco[jj] = 8 * ((lane & 7) ^ (vro[jj] & 7));
  }

  #pragma unroll 1
  for (int half = 0; half < 2; half++){
    const int j = half ? pid : 15 - pid;
    const int qr = j * 128 + wid * 16;
    const int nt = 2 * j + 2;

    bf16x8 qf[4];
    #pragma unroll
    for (int c = 0; c < 4; c++)
      qf[c] = *reinterpret_cast<const bf16x8*>(
          Q + ((size_t)bh * S_LEN + qr + fr) * DK + c * 32 + fq * 8);

    float mi[4], li[4];
    #pragma unroll
    for (int i = 0; i < 4; i++){ mi[i] = -1e30f; li[i] = 0.f; }
    f32x4 accO[8] = {};

    __syncthreads();
    #pragma unroll
    for (int jj = 0; jj < 2; jj++){
      int ins = wid * 2 + jj;
      gload16(kb + (size_t)kro[jj] * DK + kco[jj],      (char*)Kt + ins * 1024);
      gload16(vb + (size_t)vro[jj] * S_LEN + vco[jj],   (char*)Vl + ins * 1024);
    }
    __syncthreads();

    #pragma unroll 1
    for (int kt = 0; kt < nt; kt++){
      const int k0 = kt * 64;
      const int cur = kt & 1;
      if (kt + 1 < nt){
        const int k1 = k0 + 64;
        #pragma unroll
        for (int jj = 0; jj < 2; jj++){
          int ins = wid * 2 + jj;
          gload16(kb + (size_t)(k1 + kro[jj]) * DK + kco[jj],  (char*)Kt + (cur ^ 1) * 16384 + ins * 1024);
          gload16(vb + (size_t)vro[jj] * S_LEN + k1 + vco[jj], (char*)Vl + (cur ^ 1) * 16384 + ins * 1024);
        }
      }
      const char* KtB = (const char*)Kt + cur * 16384;
      const char* VlB = (const char*)Vl + cur * 16384;

      f32x4 sc[4] = {};
      #pragma unroll
      for (int c = 0; c < 4; c++){
        bf16x8 kf[4];
        #pragma unroll
        for (int ch = 0; ch < 4; ch++)
          kf[ch] = *reinterpret_cast<const bf16x8*>(
              KtB + (ch * 16 + fr) * 256 + ((c * 64 + fq * 16) ^ swz));
        #pragma unroll
        for (int ch = 0; ch < 4; ch++)
          sc[ch] = __builtin_amdgcn_mfma_f32_16x16x32_bf16(qf[c], kf[ch], sc[ch], 0, 0, 0);
      }

      const bool needmask = (k0 + 63 > qr);
      #pragma unroll
      for (int ch = 0; ch < 4; ch++)
        #pragma unroll
        for (int i = 0; i < 4; i++){
          float v = sc[ch][i] * scale;
          if (needmask && (k0 + ch * 16 + fr > qr + fq * 4 + i)) v = -1e30f;
          sc[ch][i] = v;
        }
      f32x4 mx;
      #pragma unroll
      for (int i = 0; i < 4; i++)
        mx[i] = fmaxf(fmaxf(sc[0][i], sc[1][i]), fmaxf(sc[2][i], sc[3][i]));
      #pragma unroll
      for (int off = 1; off < 16; off <<= 1)
        #pragma unroll
        for (int i = 0; i < 4; i++) mx[i] = fmaxf(mx[i], __shfl_xor(mx[i], off));
      float scl[4];
      #pragma unroll
      for (int i = 0; i < 4; i++){
        float mn = fmaxf(mi[i], mx[i]);
        scl[i] = __expf(mi[i] - mn);
        mi[i] = mn;
      }
      #pragma unroll
      for (int ch = 0; ch < 4; ch++)
        #pragma unroll
        for (int i = 0; i < 4; i++) sc[ch][i] = __expf(sc[ch][i] - mi[i]);
      f32x4 rs;
      #pragma unroll
      for (int i = 0; i < 4; i++)
        rs[i] = (sc[0][i] + sc[1][i]) + (sc[2][i] + sc[3][i]);
      #pragma unroll
      for (int off = 1; off < 16; off <<= 1)
        #pragma unroll
        for (int i = 0; i < 4; i++) rs[i] += __shfl_xor(rs[i], off);
      #pragma unroll
      for (int i = 0; i < 4; i++) li[i] = li[i] * scl[i] + rs[i];
      #pragma unroll
      for (int dt = 0; dt < 8; dt++)
        #pragma unroll
        for (int i = 0; i < 4; i++) accO[dt][i] *= scl[i];

      #pragma unroll
      for (int ch = 0; ch < 4; ch++)
        #pragma unroll
        for (int i = 0; i < 4; i++){
          int q = fq * 4 + i;
          int off = q * 128 + ((ch * 32 + fr * 2) ^ ((q & 7) << 4));
          *reinterpret_cast<short*>(PlB + off) = (short)f2bf(sc[ch][i]);
        }
      bf16x8 pf[2];
      #pragma unroll
      for (int c2 = 0; c2 < 2; c2++)
        pf[c2] = *reinterpret_cast<const bf16x8*>(
            PlB + fr * 128 + ((c2 * 64 + fq * 16) ^ swz));

      #pragma unroll
      for (int dt = 0; dt < 8; dt++)
        #pragma unroll
        for (int c2 = 0; c2 < 2; c2++){
          bf16x8 vf = *reinterpret_cast<const bf16x8*>(
              VlB + (dt * 16 + fr) * 128 + ((c2 * 64 + fq * 16) ^ swz));
          accO[dt] = __builtin_amdgcn_mfma_f32_16x16x32_bf16(pf[c2], vf, accO[dt], 0, 0, 0);
        }
      __syncthreads();
    }

    float inv[4];
    #pragma unroll
    for (int i = 0; i < 4; i++) inv[i] = 1.f / li[i];
    #pragma unroll
    for (int dt = 0; dt < 8; dt++)
      #pragma unroll
      for (int i = 0; i < 4; i++){
        int row = qr + fq * 4 + i;
        ob[(size_t)row * DM + h * DK + dt * 16 + fr] = f2bf(accO[dt][i] * inv[i]);
      }
  }
}

extern "C" void kernel_launch(void* const* d_in, const int* in_sizes, int n_in,
                              void* d_out, int out_size, void* d_ws, size_t ws_size,
                              hipStream_t stream){
  const float* x  = (const float*)d_in[0];
  const float* wq = (const float*)d_in[1];
  const float* wk = (const float*)d_in[2];
  const float* wv = (const float*)d_in[3];
  const float* wo = (const float*)d_in[4];
  const int* pos  = (const int*)d_in[5];
  float* out = (float*)d_out;

  char* ws = (char*)d_ws;
  ushort* xb   = (ushort*)(ws);               // 16 MiB; Ob aliases after GEMMs consume xb
  ushort* Ob   = xb;
  ushort* wqkv = (ushort*)(ws + 16777216);    // 24 MiB
  ushort* Qh   = (ushort*)(ws + 41943040);    // 16 MiB
  ushort* Kh   = (ushort*)(ws + 58720256);    // 16 MiB
  ushort* Vt   = (ushort*)(ws + 75497472);    // 16 MiB
  float2* cs   = (float2*)(ws + 92274688);    // 1 MiB
  ushort* wob  = (ushort*)(ws + 93323264);    // 8 MiB

  const int M = BB * S_LEN;                    // 4096

  k_rope_table<<<(S_LEN * 64) / 256, 256, 0, stream>>>(pos, cs);
  k_f32_to_bf16<<<(M * DM / 4) / 256, 256, 0, stream>>>(x, xb, M * DM / 4);
  k_w4<<<4 * (DM * DM / 4) / 256, 256, 0, stream>>>(wq, wk, wv, wo, wqkv, wob);

  k_gemm_qk<<<256, 512, 0, stream>>>(xb, wqkv, cs, Qh, Kh);
  k_gemm_v<<<256, 512, 0, stream>>>(xb, wqkv + (size_t)2 * DM * DM, Vt);

  k_attn<<<256, 512, 0, stream>>>(Qh, Kh, Vt, Ob);

  k_gemm_wo<<<256, 512, 0, stream>>>(Ob, wob, out);
}